// Round 10
// baseline (565.865 us; speedup 1.0000x reference)
//
#include <hip/hip_runtime.h>
#include <math.h>

// Problem constants
#define L_LAYERS 2
#define DM   128
#define DI   256
#define DS   16
#define DTR  8
#define DFF  256
#define PLEN 16
#define BSEQ 32
#define TSEQ 1024
#define MTOK (BSEQ*TSEQ)   // 32768
#define NCH  64            // scan chunks
#define CSZ  16            // TSEQ/NCH
#define XDW  288           // delta(256) | B(16) | C(16)
#define XDWP 320           // padded rows for delta weight

#define EPI_SPLIT2 0
#define EPI_DELTA  3

typedef unsigned short ushort_t;
typedef __attribute__((ext_vector_type(8))) short short8;
typedef __attribute__((ext_vector_type(4))) float f32x4;
#define MFMA16(a,b,c) __builtin_amdgcn_mfma_f32_16x16x32_bf16(a,b,c,0,0,0)

__device__ __forceinline__ float silu_f(float x){ return x / (1.f + __expf(-x)); }
__device__ __forceinline__ float gelu_f(float x){ return 0.5f*x*(1.f + erff(x*0.7071067811865475f)); }
__device__ __forceinline__ float softplus_f(float x){ return (x > 20.f) ? x : log1pf(__expf(x)); }

__device__ __forceinline__ ushort_t f2bf(float f){
    unsigned int u = __float_as_uint(f);
    u += 0x7fffu + ((u >> 16) & 1u);
    return (ushort_t)(u >> 16);
}
__device__ __forceinline__ float bf2f(ushort_t h){
    return __uint_as_float(((unsigned int)h) << 16);
}

// Check A[s] ~= A[0]*(s+1) (true for the reference A_log = log(1..16) tiled).
__device__ __forceinline__ bool a_structured(const float* A){
    bool ok = (A[0] < 0.f);
#pragma unroll
    for (int s=1;s<16;s++){
        float r = A[s]/A[0];
        ok = ok && (fabsf(r - (float)(s+1)) <= 1e-3f);
    }
    return ok;
}

// pk[s] = p^(s+1), log-depth multiply ladder (registers only)
__device__ __forceinline__ void pk_ladder(float p, float* pk){
    float p2 = p*p;
    float p3 = p2*p;
    float p4 = p2*p2;
    float p5 = p4*p, p6 = p4*p2, p7 = p4*p3, p8 = p4*p4;
    pk[0]=p;  pk[1]=p2; pk[2]=p3; pk[3]=p4;
    pk[4]=p5; pk[5]=p6; pk[6]=p7; pk[7]=p8;
    pk[8]=p8*p;  pk[9]=p8*p2;  pk[10]=p8*p3;  pk[11]=p8*p4;
    pk[12]=p8*p5; pk[13]=p8*p6; pk[14]=p8*p7; pk[15]=p8*p8;
}

// ---------------------------------------------------------------------------
// Patch embedding -> h (single bf16 plane)
__global__ __launch_bounds__(256) void patch_embed(
    const float* __restrict__ x, const float* __restrict__ Wp,
    const float* __restrict__ bp, ushort_t* __restrict__ hB)
{
    int bv = blockIdx.x, n0 = blockIdx.y * 64;
    __shared__ float xs[PLEN][64];
    __shared__ float ws[PLEN][DM];
    __shared__ float bs[DM];
    int tid = threadIdx.x;
    {
        int c = tid & 63, r0 = tid >> 6;
        for (int p = r0; p < PLEN; p += 4)
            xs[p][c] = x[bv*(PLEN*TSEQ) + p*TSEQ + n0 + c];
    }
    for (int i = tid; i < DM*PLEN; i += 256) {
        int d = i >> 4, p = i & 15;
        ws[p][d] = Wp[i];
    }
    if (tid < DM) bs[tid] = bp[tid];
    __syncthreads();
    int tm = tid & 15;
    int tn = tid >> 4;
    float acc[4][8];
#pragma unroll
    for (int i=0;i<4;i++)
#pragma unroll
        for (int j=0;j<8;j++) acc[i][j] = bs[tn*8+j];
#pragma unroll
    for (int p=0;p<PLEN;p++) {
        float4 a = *(const float4*)&xs[p][tm*4];
        float4 w0 = *(const float4*)&ws[p][tn*8];
        float4 w1 = *(const float4*)&ws[p][tn*8+4];
        const float* ap = (const float*)&a;
        const float* wp0 = (const float*)&w0;
        const float* wp1 = (const float*)&w1;
#pragma unroll
        for (int i=0;i<4;i++){
#pragma unroll
            for (int j=0;j<4;j++){
                acc[i][j]   += ap[i]*wp0[j];
                acc[i][j+4] += ap[i]*wp1[j];
            }
        }
    }
#pragma unroll
    for (int i=0;i<4;i++){
        size_t row = (size_t)(bv*TSEQ + n0 + tm*4 + i)*DM + tn*8;
        short8 hv;
#pragma unroll
        for (int j=0;j<8;j++) hv[j] = (short)f2bf(acc[i][j]);
        *(short8*)&hB[row] = hv;
    }
}

// ---------------------------------------------------------------------------
// Weight prep: fp32 [N][K] -> bf16 hi/lo planes (weights stay split)
__global__ __launch_bounds__(256) void prep_split(
    const float* __restrict__ src, ushort_t* __restrict__ dh, ushort_t* __restrict__ dl,
    int n_elems)
{
    int idx = blockIdx.x*256 + threadIdx.x;
    if (idx >= n_elems) return;
    float v = src[idx];
    ushort_t hi = f2bf(v);
    dh[idx] = hi;
    dl[idx] = f2bf(v - bf2f(hi));
}

// Combined x_proj weight: rows 0..255 = dtW @ xpW_dt, 256..287 = B/C rows,
// 288..319 = 0. Split planes [320][256].
__global__ __launch_bounds__(256) void prep_wcomb(
    const float* __restrict__ xpW, const float* __restrict__ dtW,
    ushort_t* __restrict__ wh, ushort_t* __restrict__ wl)
{
    int n = blockIdx.x;        // 0..319
    int k = threadIdx.x;       // 0..255
    float v = 0.f;
    if (n < 256) {
#pragma unroll
        for (int r=0;r<8;r++) v += dtW[n*8+r]*xpW[r*256+k];
    } else if (n < XDW) {
        v = xpW[(n-256+DTR)*256 + k];
    }
    ushort_t hi = f2bf(v);
    wh[n*256+k] = hi;
    wl[n*256+k] = f2bf(v - bf2f(hi));
}

// ---------------------------------------------------------------------------
// Streaming MFMA GEMM: C[M,*] = A[M,KT] @ W[*,KT]^T
// A single bf16 plane; W split hi/lo (2-term). Weights cached in LDS once
// (XOR-swizzled); K-loop barrier-free; A streamed from global (L3-resident).
template<int KT, int NT, int EPI>
__global__ __launch_bounds__(256) void gemm_stream(
    const ushort_t* __restrict__ A,
    const ushort_t* __restrict__ WH, const ushort_t* __restrict__ WL,
    const float* __restrict__ bias,
    ushort_t* __restrict__ o1, ushort_t* __restrict__ o2,
    float* __restrict__ CF)
{
    constexpr int NCHK = KT/8;
    constexpr int NF = NT/16;
    __shared__ ushort_t sWh[NT*KT];
    __shared__ ushort_t sWl[NT*KT];
    int m0 = blockIdx.x*256, n0 = blockIdx.y*NT;
    int tid = threadIdx.x;
    for (int i = tid; i < NT*NCHK; i += 256) {
        int nrow = i / NCHK, c = i % NCHK;
        int cs = c ^ (nrow & 7);
        *(short8*)&sWh[nrow*KT + cs*8] = *(const short8*)&WH[(size_t)(n0+nrow)*KT + c*8];
        *(short8*)&sWl[nrow*KT + cs*8] = *(const short8*)&WL[(size_t)(n0+nrow)*KT + c*8];
    }
    __syncthreads();
    int wave = tid>>6, lane = tid&63;
    int r = lane&15, g = lane>>4;
    int mw = m0 + wave*64;
    f32x4 acc[4][NF];
#pragma unroll
    for (int i=0;i<4;i++)
#pragma unroll
        for (int j=0;j<NF;j++) acc[i][j] = (f32x4){0.f,0.f,0.f,0.f};

#pragma unroll
    for (int ks = 0; ks < KT/32; ks++){
        short8 ah[4];
#pragma unroll
        for (int i=0;i<4;i++){
            size_t ga = (size_t)(mw + i*16 + r)*KT + ks*32 + g*8;
            ah[i] = *(const short8*)&A[ga];
        }
        short8 wh[NF], wl[NF];
#pragma unroll
        for (int j=0;j<NF;j++){
            int nrow = j*16 + r;
            int cs = (ks*4 + g) ^ (nrow & 7);
            wh[j] = *(const short8*)&sWh[nrow*KT + cs*8];
            wl[j] = *(const short8*)&sWl[nrow*KT + cs*8];
        }
#pragma unroll
        for (int i=0;i<4;i++)
#pragma unroll
        for (int j=0;j<NF;j++){
            acc[i][j] = MFMA16(ah[i], wh[j], acc[i][j]);
            acc[i][j] = MFMA16(ah[i], wl[j], acc[i][j]);
        }
    }
#pragma unroll
    for (int i=0;i<4;i++){
#pragma unroll
        for (int j=0;j<NF;j++){
            int nn = n0 + j*16 + r;
#pragma unroll
            for (int q=0;q<4;q++){
                int mm = mw + i*16 + g*4 + q;
                float v = acc[i][j][q];
                if (EPI == EPI_DELTA){
                    if (nn < XDW){
                        if (nn < 256) v = softplus_f(v + bias[nn]);
                        CF[(size_t)mm*XDW + nn] = v;
                    }
                } else {
                    ushort_t hv = f2bf(v);
                    if (nn < 256) o1[(size_t)mm*256 + nn] = hv;
                    else          o2[(size_t)mm*256 + nn-256] = hv;
                }
            }
        }
    }
}

// ---------------------------------------------------------------------------
// Causal depthwise conv (width 4) + bias + SiLU; single bf16 plane in/out
__global__ __launch_bounds__(256) void conv_silu(
    const ushort_t* __restrict__ xB, const float* __restrict__ cw,
    const float* __restrict__ cb, ushort_t* __restrict__ oB)
{
    int b = blockIdx.x, c0 = blockIdx.y*64, t0 = blockIdx.z*64;
    __shared__ float xin_s[67][64];
    __shared__ float cws[64][5];
    __shared__ float cbs[64];
    int tid = threadIdx.x;
    { int c = tid >> 2, k = tid & 3; cws[c][k] = cw[(c0+c)*4 + k]; }
    if (tid < 64) cbs[tid] = cb[c0+tid];
    {
        int c = tid & 63, r0 = tid >> 6;
        for (int rr = r0; rr < 67; rr += 4) {
            int t = t0 - 3 + rr;
            xin_s[rr][c] = (t >= 0) ? bf2f(xB[(size_t)(b*TSEQ + t)*DI + c0 + c]) : 0.f;
        }
    }
    __syncthreads();
#pragma unroll
    for (int p = 0; p < 16; p++) {
        int idx = p*256 + tid;
        int tl = idx >> 6, cl = idx & 63;
        float v = cbs[cl];
#pragma unroll
        for (int k=0;k<4;k++) v += cws[cl][k]*xin_s[tl+k][cl];
        oB[(size_t)(b*TSEQ + t0 + tl)*DI + c0 + cl] = f2bf(silu_f(v));
    }
}

// ---------------------------------------------------------------------------
// Scan pass 1: per (b, chunk, d): local end-state (h_start=0) and sum(delta)
__global__ __launch_bounds__(256) void scan_pass1(
    const float* __restrict__ xdc, const ushort_t* __restrict__ xcB,
    const float* __restrict__ Alog,
    float* __restrict__ hloc, float* __restrict__ sd)
{
    int b = blockIdx.x, c = blockIdx.y;
    int d = threadIdx.x;
    __shared__ float Bs[CSZ][16];
    int mbase = b*TSEQ + c*CSZ;
    for (int i = d; i < CSZ*16; i += 256) {
        int t = i >> 4, s = i & 15;
        Bs[t][s] = xdc[(size_t)(mbase+t)*XDW + 256 + s];
    }
    float A[16], h[16];
    {
        float4 a0 = *(const float4*)&Alog[d*16];
        float4 a1 = *(const float4*)&Alog[d*16+4];
        float4 a2 = *(const float4*)&Alog[d*16+8];
        float4 a3 = *(const float4*)&Alog[d*16+12];
        float tmp[16] = {a0.x,a0.y,a0.z,a0.w,a1.x,a1.y,a1.z,a1.w,
                         a2.x,a2.y,a2.z,a2.w,a3.x,a3.y,a3.z,a3.w};
#pragma unroll
        for (int s=0;s<16;s++){ A[s] = -__expf(tmp[s]); h[s] = 0.f; }
    }
    bool structured = a_structured(A);
    float A0 = A[0];
    float sdv = 0.f;
    __syncthreads();
    if (structured) {
#pragma unroll 4
        for (int t=0;t<CSZ;t++){
            size_t m = (size_t)(mbase+t);
            float dlt = xdc[m*XDW + d];
            float u = bf2f(xcB[m*DI + d]);
            sdv += dlt;
            float du = dlt*u;
            float pk[16];
            pk_ladder(__expf(dlt*A0), pk);
#pragma unroll
            for (int s=0;s<16;s++)
                h[s] = pk[s]*h[s] + du*Bs[t][s];
        }
    } else {
#pragma unroll 4
        for (int t=0;t<CSZ;t++){
            size_t m = (size_t)(mbase+t);
            float dlt = xdc[m*XDW + d];
            float u = bf2f(xcB[m*DI + d]);
            sdv += dlt;
            float du = dlt*u;
#pragma unroll
            for (int s=0;s<16;s++)
                h[s] = __expf(dlt*A[s])*h[s] + du*Bs[t][s];
        }
    }
#pragma unroll
    for (int s=0;s<16;s++)
        hloc[((size_t)((b*NCH + c)*16 + s))*DI + d] = h[s];
    sd[(b*NCH + c)*DI + d] = sdv;
}

// ---------------------------------------------------------------------------
// Prefix-combine over chunks (thread = (b,s,d))
__global__ __launch_bounds__(256) void scan_combine(
    const float* __restrict__ hloc, const float* __restrict__ sd,
    const float* __restrict__ Alog, float* __restrict__ hstart)
{
    int b = blockIdx.x, s = blockIdx.y;
    int d = threadIdx.x;
    float A = -__expf(Alog[d*16+s]);
    float hs = 0.f;
    for (int c = 0; c < NCH; c++){
        size_t base = ((size_t)((b*NCH + c)*16 + s))*DI + d;
        hstart[base] = hs;
        float sdp = sd[(b*NCH + c)*DI + d];
        hs = __expf(sdp*A)*hs + hloc[base];
    }
}

// ---------------------------------------------------------------------------
// Fused scan pass 2 + out_proj + FFN (gelu) for a 16-token chunk.
// Single-plane activations. LDS: yB [16][264] bf16 (8448 B);
// region2 = union( oB [16][136] bf16 (4352 B), Bs/Cs fp32 (2048 B) ).
// Total 12800 B; grid 2048 blocks = 8/CU; VGPR ~68 -> ~7 blocks/CU resident.
__global__ __launch_bounds__(256,3) void scan_fused(
    const float* __restrict__ xdc,
    const ushort_t* __restrict__ xcB, const ushort_t* __restrict__ zB,
    const float* __restrict__ Alog, const float* __restrict__ Dp,
    const float* __restrict__ hstart,
    const ushort_t* __restrict__ oWh, const ushort_t* __restrict__ oWl,
    const ushort_t* __restrict__ w1h, const ushort_t* __restrict__ w1l,
    const float* __restrict__ b1,
    const ushort_t* __restrict__ w2h, const ushort_t* __restrict__ w2l,
    const float* __restrict__ b2,
    ushort_t* __restrict__ hB)
{
    constexpr int YS = DI + 8;    // 264 shorts (row stride 528 B, 16-aligned)
    constexpr int OS = DM + 8;    // 136 shorts
    __shared__ __align__(16) ushort_t smem[CSZ*YS + CSZ*OS];   // 12800 B
    ushort_t* yB = smem;                      // [t*YS + d]
    ushort_t* oB = smem + CSZ*YS;             // [t*OS + n]
    float*    Bs = (float*)(smem + CSZ*YS);   // union with oB
    float*    Cs = Bs + CSZ*16;

    int b = blockIdx.x, c = blockIdx.y;
    int tid = threadIdx.x;
    int mbase = b*TSEQ + c*CSZ;
    for (int i = tid; i < CSZ*32; i += 256) {
        int t = i >> 5, s2 = i & 31;
        float v = xdc[(size_t)(mbase+t)*XDW + 256 + s2];
        if (s2 < 16) Bs[t*16+s2] = v; else Cs[t*16+s2-16] = v;
    }
    // ---- Phase A: scan
    {
        int d = tid;
        float A[16], h[16];
        float4 a0 = *(const float4*)&Alog[d*16];
        float4 a1 = *(const float4*)&Alog[d*16+4];
        float4 a2 = *(const float4*)&Alog[d*16+8];
        float4 a3 = *(const float4*)&Alog[d*16+12];
        float tmp[16] = {a0.x,a0.y,a0.z,a0.w,a1.x,a1.y,a1.z,a1.w,
                         a2.x,a2.y,a2.z,a2.w,a3.x,a3.y,a3.z,a3.w};
#pragma unroll
        for (int s=0;s<16;s++) A[s] = -__expf(tmp[s]);
        bool structured = a_structured(A);
        float A0 = A[0];
#pragma unroll
        for (int s=0;s<16;s++)
            h[s] = hstart[((size_t)((b*NCH + c)*16 + s))*DI + d];
        float Dd = Dp[d];
        __syncthreads();
        if (structured) {
#pragma unroll 2
            for (int t=0;t<CSZ;t++){
                size_t m = (size_t)(mbase+t);
                float dlt = xdc[m*XDW + d];
                float u = bf2f(xcB[m*DI + d]);
                float z = bf2f(zB[m*DI + d]);
                float du = dlt*u;
                float pk[16];
                pk_ladder(__expf(dlt*A0), pk);
                float y0=0.f, y1=0.f, y2=0.f, y3=0.f;
#pragma unroll
                for (int s=0;s<16;s+=4){
                    h[s]   = pk[s]*h[s]     + du*Bs[t*16+s];   y0 += h[s]*Cs[t*16+s];
                    h[s+1] = pk[s+1]*h[s+1] + du*Bs[t*16+s+1]; y1 += h[s+1]*Cs[t*16+s+1];
                    h[s+2] = pk[s+2]*h[s+2] + du*Bs[t*16+s+2]; y2 += h[s+2]*Cs[t*16+s+2];
                    h[s+3] = pk[s+3]*h[s+3] + du*Bs[t*16+s+3]; y3 += h[s+3]*Cs[t*16+s+3];
                }
                float y = (y0+y1)+(y2+y3);
                yB[t*YS+d] = f2bf((y + u*Dd) * silu_f(z));
            }
        } else {
#pragma unroll 2
            for (int t=0;t<CSZ;t++){
                size_t m = (size_t)(mbase+t);
                float dlt = xdc[m*XDW + d];
                float u = bf2f(xcB[m*DI + d]);
                float z = bf2f(zB[m*DI + d]);
                float du = dlt*u;
                float y0=0.f, y1=0.f, y2=0.f, y3=0.f;
#pragma unroll
                for (int s=0;s<16;s+=4){
                    h[s]   = __expf(dlt*A[s])*h[s]     + du*Bs[t*16+s];   y0 += h[s]*Cs[t*16+s];
                    h[s+1] = __expf(dlt*A[s+1])*h[s+1] + du*Bs[t*16+s+1]; y1 += h[s+1]*Cs[t*16+s+1];
                    h[s+2] = __expf(dlt*A[s+2])*h[s+2] + du*Bs[t*16+s+2]; y2 += h[s+2]*Cs[t*16+s+2];
                    h[s+3] = __expf(dlt*A[s+3])*h[s+3] + du*Bs[t*16+s+3]; y3 += h[s+3]*Cs[t*16+s+3];
                }
                float y = (y0+y1)+(y2+y3);
                yB[t*YS+d] = f2bf((y + u*Dd) * silu_f(z));
            }
        }
    }
    __syncthreads();   // yB done; Bs/Cs dead -> region2 reusable as oB
    // ---- Phase B (16-row tiles)
    int wave = tid>>6, lane = tid&63;
    int r = lane&15, g = lane>>4;
    // Stage 1: o[16][128] = y @ oW^T  (K=256)
    {
        f32x4 s1[2];
#pragma unroll
        for (int j=0;j<2;j++) s1[j] = (f32x4){0.f,0.f,0.f,0.f};
#pragma unroll
        for (int ks=0;ks<8;ks++){
            short8 ya = *(const short8*)&yB[r*YS + ks*32 + g*8];
            short8 wh_[2], wl_[2];
#pragma unroll
            for (int j=0;j<2;j++){
                size_t wa = (size_t)(wave*32 + j*16 + r)*256 + ks*32 + g*8;
                wh_[j] = *(const short8*)&oWh[wa];
                wl_[j] = *(const short8*)&oWl[wa];
            }
#pragma unroll
            for (int j=0;j<2;j++){
                s1[j] = MFMA16(ya, wh_[j], s1[j]);
                s1[j] = MFMA16(ya, wl_[j], s1[j]);
            }
        }
#pragma unroll
        for (int j=0;j<2;j++)
#pragma unroll
        for (int q=0;q<4;q++){
            int t = g*4 + q;
            int n = wave*32 + j*16 + r;
            oB[t*OS+n] = f2bf(s1[j][q]);
        }
    }
    __syncthreads();   // oB ready; yB reads done
    // Stage 2: f[16][256] = gelu(o @ w1^T + b1)  (K=128), into yB
    {
        f32x4 s2[4];
#pragma unroll
        for (int j=0;j<4;j++) s2[j] = (f32x4){0.f,0.f,0.f,0.f};
#pragma unroll
        for (int ks=0;ks<4;ks++){
            short8 oa = *(const short8*)&oB[r*OS + ks*32 + g*8];
            short8 wh_[4], wl_[4];
#pragma unroll
            for (int j=0;j<4;j++){
                size_t wa = (size_t)(wave*64 + j*16 + r)*128 + ks*32 + g*8;
                wh_[j] = *(const short8*)&w1h[wa];
                wl_[j] = *(const short8*)&w1l[wa];
            }
#pragma unroll
            for (int j=0;j<4;j++){
                s2[j] = MFMA16(oa, wh_[j], s2[j]);
                s2[j] = MFMA16(oa, wl_[j], s2[j]);
            }
        }
        __syncthreads();   // all waves done reading oB before yB overwrite is fine (yB untouched here), but keep stage2 reads of oB complete before any later reuse
#pragma unroll
        for (int j=0;j<4;j++)
#pragma unroll
        for (int q=0;q<4;q++){
            int t = g*4 + q;
            int n = wave*64 + j*16 + r;
            yB[t*YS+n] = f2bf(gelu_f(s2[j][q] + b1[n]));
        }
    }
    __syncthreads();   // f (in yB) done
    // Stage 3: hnew[16][128] = f @ w2^T + b2  (K=256) -> global plane
    {
        f32x4 s3[2];
#pragma unroll
        for (int j=0;j<2;j++) s3[j] = (f32x4){0.f,0.f,0.f,0.f};
#pragma unroll
        for (int ks=0;ks<8;ks++){
            short8 fa = *(const short8*)&yB[r*YS + ks*32 + g*8];
            short8 wh_[2], wl_[2];
#pragma unroll
            for (int j=0;j<2;j++){
                size_t wa = (size_t)(wave*32 + j*16 + r)*256 + ks*32 + g*8;
                wh_[j] = *(const short8*)&w2h[wa];
                wl_[j] = *(const short8*)&w2l[wa];
            }
#pragma unroll
            for (int j=0;j<2;j++){
                s3[j] = MFMA16(fa, wh_[j], s3[j]);
                s3[j] = MFMA16(fa, wl_[j], s3[j]);
            }
        }
#pragma unroll
        for (int j=0;j<2;j++)
#pragma unroll
        for (int q=0;q<4;q++){
            int t = g*4 + q;
            int n = wave*32 + j*16 + r;
            hB[(size_t)(mbase + t)*DM + n] = f2bf(s3[j][q] + b2[n]);
        }
    }
}

// ---------------------------------------------------------------------------
// Final transpose: out[bv, d, n] = h[bv*1024+n, d]
__global__ __launch_bounds__(256) void final_transpose(
    const ushort_t* __restrict__ hB, float* __restrict__ out)
{
    int n0 = blockIdx.x*32, d0 = blockIdx.y*32, bv = blockIdx.z;
    __shared__ float ts[32][33];
    int tid = threadIdx.x;
    int c = tid & 31, r0 = tid >> 5;
    for (int rr = r0; rr < 32; rr += 8)
        ts[rr][c] = bf2f(hB[(size_t)(bv*TSEQ + n0 + rr)*DM + d0 + c]);
    __syncthreads();
    for (int rr = r0; rr < 32; rr += 8)
        out[(size_t)(bv*DM + d0 + rr)*TSEQ + n0 + c] = ts[c][rr];
}

// ---------------------------------------------------------------------------
extern "C" void kernel_launch(void* const* d_in, const int* in_sizes, int n_in,
                              void* d_out, int out_size, void* d_ws, size_t ws_size,
                              hipStream_t stream)
{
    const float* x     = (const float*)d_in[0];
    const float* Wp    = (const float*)d_in[1];
    const float* Wpb   = (const float*)d_in[2];
    const float* inW   = (const float*)d_in[3];
    const float* convW = (const float*)d_in[4];
    const float* convB = (const float*)d_in[5];
    const float* xpW   = (const float*)d_in[6];
    const float* dtW   = (const float*)d_in[7];
    const float* dtB   = (const float*)d_in[8];
    const float* Alog  = (const float*)d_in[9];
    const float* Dp    = (const float*)d_in[10];
    const float* outW  = (const float*)d_in[11];
    const float* l1W   = (const float*)d_in[12];
    const float* l1B   = (const float*)d_in[13];
    const float* l2W   = (const float*)d_in[14];
    const float* l2B   = (const float*)d_in[15];
    float* out = (float*)d_out;

    char* base = (char*)d_ws;
    size_t off = 0;
    auto alloc = [&](size_t bytes) { char* p = base + off; off += (bytes + 255) & ~(size_t)255; return p; };

    const size_t P128 = (size_t)MTOK*DM*2;     // [M][128] bf16 plane
    const size_t P256 = (size_t)MTOK*DI*2;     // [M][256] bf16 plane

    ushort_t* hB  = (ushort_t*)alloc(P128);
    // slab1: xin plane (16.8MB) UNION xdc fp32 (37.75MB)
    char* slab1 = alloc((size_t)MTOK*XDW*4);
    ushort_t* xinB = (ushort_t*)slab1;
    float*    xdc  = (float*)slab1;
    ushort_t* zB  = (ushort_t*)alloc(P256);
    ushort_t* xcB = (ushort_t*)alloc(P256);
    float* hloc   = (float*)alloc((size_t)BSEQ*NCH*DS*DI*4);
    float* hstart = (float*)alloc((size_t)BSEQ*NCH*DS*DI*4);
    float* sd     = (float*)alloc((size_t)BSEQ*NCH*DI*4);
    ushort_t* inWh  = (ushort_t*)alloc((size_t)512*128*2);
    ushort_t* inWl  = (ushort_t*)alloc((size_t)512*128*2);
    ushort_t* wcH   = (ushort_t*)alloc((size_t)XDWP*256*2);
    ushort_t* wcL   = (ushort_t*)alloc((size_t)XDWP*256*2);
    ushort_t* outWh = (ushort_t*)alloc((size_t)128*256*2);
    ushort_t* outWl = (ushort_t*)alloc((size_t)128*256*2);
    ushort_t* l1Wh  = (ushort_t*)alloc((size_t)256*128*2);
    ushort_t* l1Wl  = (ushort_t*)alloc((size_t)256*128*2);
    ushort_t* l2Wh  = (ushort_t*)alloc((size_t)128*256*2);
    ushort_t* l2Wl  = (ushort_t*)alloc((size_t)128*256*2);

    patch_embed<<<dim3(32,16), 256, 0, stream>>>(x, Wp, Wpb, hB);

    for (int L = 0; L < L_LAYERS; L++) {
        const float* inW_l   = inW   + (size_t)L*2*DI*DM;
        const float* convW_l = convW + (size_t)L*DI*4;
        const float* convB_l = convB + (size_t)L*DI;
        const float* xpW_l   = xpW   + (size_t)L*(DTR+2*DS)*DI;
        const float* dtW_l   = dtW   + (size_t)L*DI*DTR;
        const float* dtB_l   = dtB   + (size_t)L*DI;
        const float* Alog_l  = Alog  + (size_t)L*DI*DS;
        const float* Dp_l    = Dp    + (size_t)L*DI;
        const float* outW_l  = outW  + (size_t)L*DM*DI;
        const float* l1W_l   = l1W   + (size_t)L*DFF*DM;
        const float* l1B_l   = l1B   + (size_t)L*DFF;
        const float* l2W_l   = l2W   + (size_t)L*DM*DFF;
        const float* l2B_l   = l2B   + (size_t)L*DM;

        // ---- weight prep (weights stay split hi/lo)
        prep_split<<<(512*128+255)/256, 256, 0, stream>>>(inW_l, inWh, inWl, 512*128);
        prep_wcomb<<<XDWP, 256, 0, stream>>>(xpW_l, dtW_l, wcH, wcL);
        prep_split<<<(128*256+255)/256, 256, 0, stream>>>(outW_l, outWh, outWl, 128*256);
        prep_split<<<(256*128+255)/256, 256, 0, stream>>>(l1W_l, l1Wh, l1Wl, 256*128);
        prep_split<<<(128*256+255)/256, 256, 0, stream>>>(l2W_l, l2Wh, l2Wl, 128*256);

        // ---- in_proj: [M,512] = h @ inW^T, K=128; routes cols to xin / z
        gemm_stream<128,64,EPI_SPLIT2><<<dim3(MTOK/256, 8), 256, 0, stream>>>(
            hB, inWh, inWl, nullptr, xinB, zB, nullptr);
        // ---- conv + silu
        conv_silu<<<dim3(BSEQ, DI/64, TSEQ/64), 256, 0, stream>>>(
            xinB, convW_l, convB_l, xcB);
        // ---- delta|B|C GEMM: [M,288] = xc @ wc^T, K=256 (softplus on delta)
        gemm_stream<256,32,EPI_DELTA><<<dim3(MTOK/256, XDWP/32), 256, 0, stream>>>(
            xcB, wcH, wcL, dtB_l, nullptr, nullptr, xdc);
        // ---- chunked scan
        scan_pass1<<<dim3(BSEQ, NCH), 256, 0, stream>>>(
            xdc, xcB, Alog_l, hloc, sd);
        scan_combine<<<dim3(BSEQ, DS), 256, 0, stream>>>(
            hloc, sd, Alog_l, hstart);
        // ---- fused scan pass2 + out_proj + FFN
        scan_fused<<<dim3(BSEQ, NCH), 256, 0, stream>>>(
            xdc, xcB, zB, Alog_l, Dp_l, hstart,
            outWh, outWl, l1Wh, l1Wl, l1B_l, l2Wh, l2Wl, l2B_l, hB);
    }

    final_transpose<<<dim3(TSEQ/32, DM/32, BSEQ), 256, 0, stream>>>(hB, out);
}

// Round 11
// 519.420 us; speedup vs baseline: 1.0894x; 1.0894x over previous
//
#include <hip/hip_runtime.h>
#include <math.h>

// Problem constants
#define L_LAYERS 2
#define DM   128
#define DI   256
#define DS   16
#define DTR  8
#define DFF  256
#define PLEN 16
#define BSEQ 32
#define TSEQ 1024
#define MTOK (BSEQ*TSEQ)   // 32768
#define NCH  32            // scan chunks
#define CSZ  32            // TSEQ/NCH
#define XDW  288           // delta(256) | B(16) | C(16)
#define XDWP 320           // padded rows for delta weight

#define EPI_SPLIT2 0
#define EPI_DELTA  3

typedef unsigned short ushort_t;
typedef __attribute__((ext_vector_type(8))) short short8;
typedef __attribute__((ext_vector_type(4))) float f32x4;
#define MFMA16(a,b,c) __builtin_amdgcn_mfma_f32_16x16x32_bf16(a,b,c,0,0,0)

__device__ __forceinline__ float silu_f(float x){ return x / (1.f + __expf(-x)); }
__device__ __forceinline__ float gelu_f(float x){ return 0.5f*x*(1.f + erff(x*0.7071067811865475f)); }
__device__ __forceinline__ float softplus_f(float x){ return (x > 20.f) ? x : log1pf(__expf(x)); }

__device__ __forceinline__ ushort_t f2bf(float f){
    unsigned int u = __float_as_uint(f);
    u += 0x7fffu + ((u >> 16) & 1u);
    return (ushort_t)(u >> 16);
}
__device__ __forceinline__ float bf2f(ushort_t h){
    return __uint_as_float(((unsigned int)h) << 16);
}

// Check A[s] ~= A[0]*(s+1) (true for the reference A_log = log(1..16) tiled).
__device__ __forceinline__ bool a_structured(const float* A){
    bool ok = (A[0] < 0.f);
#pragma unroll
    for (int s=1;s<16;s++){
        float r = A[s]/A[0];
        ok = ok && (fabsf(r - (float)(s+1)) <= 1e-3f);
    }
    return ok;
}

// pk[s] = p^(s+1), log-depth multiply ladder (registers only)
__device__ __forceinline__ void pk_ladder(float p, float* pk){
    float p2 = p*p;
    float p3 = p2*p;
    float p4 = p2*p2;
    float p5 = p4*p, p6 = p4*p2, p7 = p4*p3, p8 = p4*p4;
    pk[0]=p;  pk[1]=p2; pk[2]=p3; pk[3]=p4;
    pk[4]=p5; pk[5]=p6; pk[6]=p7; pk[7]=p8;
    pk[8]=p8*p;  pk[9]=p8*p2;  pk[10]=p8*p3;  pk[11]=p8*p4;
    pk[12]=p8*p5; pk[13]=p8*p6; pk[14]=p8*p7; pk[15]=p8*p8;
}

// ---------------------------------------------------------------------------
// Patch embedding -> h (single bf16 plane)
__global__ __launch_bounds__(256) void patch_embed(
    const float* __restrict__ x, const float* __restrict__ Wp,
    const float* __restrict__ bp, ushort_t* __restrict__ hB)
{
    int bv = blockIdx.x, n0 = blockIdx.y * 64;
    __shared__ float xs[PLEN][64];
    __shared__ float ws[PLEN][DM];
    __shared__ float bs[DM];
    int tid = threadIdx.x;
    {
        int c = tid & 63, r0 = tid >> 6;
        for (int p = r0; p < PLEN; p += 4)
            xs[p][c] = x[bv*(PLEN*TSEQ) + p*TSEQ + n0 + c];
    }
    for (int i = tid; i < DM*PLEN; i += 256) {
        int d = i >> 4, p = i & 15;
        ws[p][d] = Wp[i];
    }
    if (tid < DM) bs[tid] = bp[tid];
    __syncthreads();
    int tm = tid & 15;
    int tn = tid >> 4;
    float acc[4][8];
#pragma unroll
    for (int i=0;i<4;i++)
#pragma unroll
        for (int j=0;j<8;j++) acc[i][j] = bs[tn*8+j];
#pragma unroll
    for (int p=0;p<PLEN;p++) {
        float4 a = *(const float4*)&xs[p][tm*4];
        float4 w0 = *(const float4*)&ws[p][tn*8];
        float4 w1 = *(const float4*)&ws[p][tn*8+4];
        const float* ap = (const float*)&a;
        const float* wp0 = (const float*)&w0;
        const float* wp1 = (const float*)&w1;
#pragma unroll
        for (int i=0;i<4;i++){
#pragma unroll
            for (int j=0;j<4;j++){
                acc[i][j]   += ap[i]*wp0[j];
                acc[i][j+4] += ap[i]*wp1[j];
            }
        }
    }
#pragma unroll
    for (int i=0;i<4;i++){
        size_t row = (size_t)(bv*TSEQ + n0 + tm*4 + i)*DM + tn*8;
        short8 hv;
#pragma unroll
        for (int j=0;j<8;j++) hv[j] = (short)f2bf(acc[i][j]);
        *(short8*)&hB[row] = hv;
    }
}

// ---------------------------------------------------------------------------
// Weight prep: fp32 [N][K] -> bf16 hi/lo planes (weights stay split)
__global__ __launch_bounds__(256) void prep_split(
    const float* __restrict__ src, ushort_t* __restrict__ dh, ushort_t* __restrict__ dl,
    int n_elems)
{
    int idx = blockIdx.x*256 + threadIdx.x;
    if (idx >= n_elems) return;
    float v = src[idx];
    ushort_t hi = f2bf(v);
    dh[idx] = hi;
    dl[idx] = f2bf(v - bf2f(hi));
}

// Combined x_proj weight: rows 0..255 = dtW @ xpW_dt, 256..287 = B/C rows,
// 288..319 = 0. Split planes [320][256].
__global__ __launch_bounds__(256) void prep_wcomb(
    const float* __restrict__ xpW, const float* __restrict__ dtW,
    ushort_t* __restrict__ wh, ushort_t* __restrict__ wl)
{
    int n = blockIdx.x;        // 0..319
    int k = threadIdx.x;       // 0..255
    float v = 0.f;
    if (n < 256) {
#pragma unroll
        for (int r=0;r<8;r++) v += dtW[n*8+r]*xpW[r*256+k];
    } else if (n < XDW) {
        v = xpW[(n-256+DTR)*256 + k];
    }
    ushort_t hi = f2bf(v);
    wh[n*256+k] = hi;
    wl[n*256+k] = f2bf(v - bf2f(hi));
}

// ---------------------------------------------------------------------------
// Streaming MFMA GEMM: C[M,*] = A[M,KT] @ W[*,KT]^T
// A single bf16 plane; W split hi/lo (2-term). Weights cached in LDS once
// (XOR-swizzled); K-loop barrier-free; A streamed from global (L3-resident).
template<int KT, int NT, int EPI>
__global__ __launch_bounds__(256) void gemm_stream(
    const ushort_t* __restrict__ A,
    const ushort_t* __restrict__ WH, const ushort_t* __restrict__ WL,
    const float* __restrict__ bias,
    ushort_t* __restrict__ o1, ushort_t* __restrict__ o2,
    float* __restrict__ CF)
{
    constexpr int NCHK = KT/8;
    constexpr int NF = NT/16;
    __shared__ ushort_t sWh[NT*KT];
    __shared__ ushort_t sWl[NT*KT];
    int m0 = blockIdx.x*256, n0 = blockIdx.y*NT;
    int tid = threadIdx.x;
    for (int i = tid; i < NT*NCHK; i += 256) {
        int nrow = i / NCHK, c = i % NCHK;
        int cs = c ^ (nrow & 7);
        *(short8*)&sWh[nrow*KT + cs*8] = *(const short8*)&WH[(size_t)(n0+nrow)*KT + c*8];
        *(short8*)&sWl[nrow*KT + cs*8] = *(const short8*)&WL[(size_t)(n0+nrow)*KT + c*8];
    }
    __syncthreads();
    int wave = tid>>6, lane = tid&63;
    int r = lane&15, g = lane>>4;
    int mw = m0 + wave*64;
    f32x4 acc[4][NF];
#pragma unroll
    for (int i=0;i<4;i++)
#pragma unroll
        for (int j=0;j<NF;j++) acc[i][j] = (f32x4){0.f,0.f,0.f,0.f};

#pragma unroll
    for (int ks = 0; ks < KT/32; ks++){
        short8 ah[4];
#pragma unroll
        for (int i=0;i<4;i++){
            size_t ga = (size_t)(mw + i*16 + r)*KT + ks*32 + g*8;
            ah[i] = *(const short8*)&A[ga];
        }
        short8 wh[NF], wl[NF];
#pragma unroll
        for (int j=0;j<NF;j++){
            int nrow = j*16 + r;
            int cs = (ks*4 + g) ^ (nrow & 7);
            wh[j] = *(const short8*)&sWh[nrow*KT + cs*8];
            wl[j] = *(const short8*)&sWl[nrow*KT + cs*8];
        }
#pragma unroll
        for (int i=0;i<4;i++)
#pragma unroll
        for (int j=0;j<NF;j++){
            acc[i][j] = MFMA16(ah[i], wh[j], acc[i][j]);
            acc[i][j] = MFMA16(ah[i], wl[j], acc[i][j]);
        }
    }
#pragma unroll
    for (int i=0;i<4;i++){
#pragma unroll
        for (int j=0;j<NF;j++){
            int nn = n0 + j*16 + r;
#pragma unroll
            for (int q=0;q<4;q++){
                int mm = mw + i*16 + g*4 + q;
                float v = acc[i][j][q];
                if (EPI == EPI_DELTA){
                    if (nn < XDW){
                        if (nn < 256) v = softplus_f(v + bias[nn]);
                        CF[(size_t)mm*XDW + nn] = v;
                    }
                } else {
                    ushort_t hv = f2bf(v);
                    if (nn < 256) o1[(size_t)mm*256 + nn] = hv;
                    else          o2[(size_t)mm*256 + nn-256] = hv;
                }
            }
        }
    }
}

// ---------------------------------------------------------------------------
// Causal depthwise conv (width 4) + bias + SiLU; single bf16 plane in/out
__global__ __launch_bounds__(256) void conv_silu(
    const ushort_t* __restrict__ xB, const float* __restrict__ cw,
    const float* __restrict__ cb, ushort_t* __restrict__ oB)
{
    int b = blockIdx.x, c0 = blockIdx.y*64, t0 = blockIdx.z*64;
    __shared__ float xin_s[67][64];
    __shared__ float cws[64][5];
    __shared__ float cbs[64];
    int tid = threadIdx.x;
    { int c = tid >> 2, k = tid & 3; cws[c][k] = cw[(c0+c)*4 + k]; }
    if (tid < 64) cbs[tid] = cb[c0+tid];
    {
        int c = tid & 63, r0 = tid >> 6;
        for (int rr = r0; rr < 67; rr += 4) {
            int t = t0 - 3 + rr;
            xin_s[rr][c] = (t >= 0) ? bf2f(xB[(size_t)(b*TSEQ + t)*DI + c0 + c]) : 0.f;
        }
    }
    __syncthreads();
#pragma unroll
    for (int p = 0; p < 16; p++) {
        int idx = p*256 + tid;
        int tl = idx >> 6, cl = idx & 63;
        float v = cbs[cl];
#pragma unroll
        for (int k=0;k<4;k++) v += cws[cl][k]*xin_s[tl+k][cl];
        oB[(size_t)(b*TSEQ + t0 + tl)*DI + c0 + cl] = f2bf(silu_f(v));
    }
}

// ---------------------------------------------------------------------------
// Scan pass 1: per (b, chunk, d): local end-state (h_start=0) and sum(delta)
// 8-deep load prefetch per group.
__global__ __launch_bounds__(256) void scan_pass1(
    const float* __restrict__ xdc, const ushort_t* __restrict__ xcB,
    const float* __restrict__ Alog,
    float* __restrict__ hloc, float* __restrict__ sd)
{
    int b = blockIdx.x, c = blockIdx.y;
    int d = threadIdx.x;
    __shared__ float Bs[CSZ][16];
    int mbase = b*TSEQ + c*CSZ;
    for (int i = d; i < CSZ*16; i += 256) {
        int t = i >> 4, s = i & 15;
        Bs[t][s] = xdc[(size_t)(mbase+t)*XDW + 256 + s];
    }
    float A[16], h[16];
    {
        float4 a0 = *(const float4*)&Alog[d*16];
        float4 a1 = *(const float4*)&Alog[d*16+4];
        float4 a2 = *(const float4*)&Alog[d*16+8];
        float4 a3 = *(const float4*)&Alog[d*16+12];
        float tmp[16] = {a0.x,a0.y,a0.z,a0.w,a1.x,a1.y,a1.z,a1.w,
                         a2.x,a2.y,a2.z,a2.w,a3.x,a3.y,a3.z,a3.w};
#pragma unroll
        for (int s=0;s<16;s++){ A[s] = -__expf(tmp[s]); h[s] = 0.f; }
    }
    bool structured = a_structured(A);
    float A0 = A[0];
    float sdv = 0.f;
    __syncthreads();
    for (int t0 = 0; t0 < CSZ; t0 += 8){
        float dl[8], uu[8];
#pragma unroll
        for (int k=0;k<8;k++){
            size_t m = (size_t)(mbase+t0+k);
            dl[k] = xdc[m*XDW + d];
            uu[k] = bf2f(xcB[m*DI + d]);
        }
        if (structured) {
#pragma unroll
            for (int k=0;k<8;k++){
                int t = t0+k;
                float dlt = dl[k];
                sdv += dlt;
                float du = dlt*uu[k];
                float pk[16];
                pk_ladder(__expf(dlt*A0), pk);
#pragma unroll
                for (int s=0;s<16;s++)
                    h[s] = pk[s]*h[s] + du*Bs[t][s];
            }
        } else {
#pragma unroll
            for (int k=0;k<8;k++){
                int t = t0+k;
                float dlt = dl[k];
                sdv += dlt;
                float du = dlt*uu[k];
#pragma unroll
                for (int s=0;s<16;s++)
                    h[s] = __expf(dlt*A[s])*h[s] + du*Bs[t][s];
            }
        }
    }
#pragma unroll
    for (int s=0;s<16;s++)
        hloc[((size_t)((b*NCH + c)*16 + s))*DI + d] = h[s];
    sd[(b*NCH + c)*DI + d] = sdv;
}

// ---------------------------------------------------------------------------
// Prefix-combine over chunks (thread = (b,s,d))
__global__ __launch_bounds__(256) void scan_combine(
    const float* __restrict__ hloc, const float* __restrict__ sd,
    const float* __restrict__ Alog, float* __restrict__ hstart)
{
    int b = blockIdx.x, s = blockIdx.y;
    int d = threadIdx.x;
    float A = -__expf(Alog[d*16+s]);
    float hs = 0.f;
    for (int c = 0; c < NCH; c++){
        size_t base = ((size_t)((b*NCH + c)*16 + s))*DI + d;
        hstart[base] = hs;
        float sdp = sd[(b*NCH + c)*DI + d];
        hs = __expf(sdp*A)*hs + hloc[base];
    }
}

// ---------------------------------------------------------------------------
// Fused scan pass 2 + out_proj + FFN (gelu) for a 32-token chunk.
// Single-plane activations; Phase A uses 8-deep load prefetch.
// LDS: yB [32][264] bf16 (16896 B);
// region2 = union( oB [32][136] bf16 (8704 B), Bs/Cs fp32 (4096 B) ).
// Total 25600 B.
__global__ __launch_bounds__(256,3) void scan_fused(
    const float* __restrict__ xdc,
    const ushort_t* __restrict__ xcB, const ushort_t* __restrict__ zB,
    const float* __restrict__ Alog, const float* __restrict__ Dp,
    const float* __restrict__ hstart,
    const ushort_t* __restrict__ oWh, const ushort_t* __restrict__ oWl,
    const ushort_t* __restrict__ w1h, const ushort_t* __restrict__ w1l,
    const float* __restrict__ b1,
    const ushort_t* __restrict__ w2h, const ushort_t* __restrict__ w2l,
    const float* __restrict__ b2,
    ushort_t* __restrict__ hB)
{
    constexpr int YS = DI + 8;    // 264 shorts (row stride 528 B, 16-aligned)
    constexpr int OS = DM + 8;    // 136 shorts
    __shared__ __align__(16) ushort_t smem[CSZ*YS + CSZ*OS];   // 25600 B
    ushort_t* yB = smem;                      // [t*YS + d]
    ushort_t* oB = smem + CSZ*YS;             // [t*OS + n]
    float*    Bs = (float*)(smem + CSZ*YS);   // union with oB
    float*    Cs = Bs + CSZ*16;

    int b = blockIdx.x, c = blockIdx.y;
    int tid = threadIdx.x;
    int mbase = b*TSEQ + c*CSZ;
    for (int i = tid; i < CSZ*32; i += 256) {
        int t = i >> 5, s2 = i & 31;
        float v = xdc[(size_t)(mbase+t)*XDW + 256 + s2];
        if (s2 < 16) Bs[t*16+s2] = v; else Cs[t*16+s2-16] = v;
    }
    // ---- Phase A: scan
    {
        int d = tid;
        float A[16], h[16];
        float4 a0 = *(const float4*)&Alog[d*16];
        float4 a1 = *(const float4*)&Alog[d*16+4];
        float4 a2 = *(const float4*)&Alog[d*16+8];
        float4 a3 = *(const float4*)&Alog[d*16+12];
        float tmp[16] = {a0.x,a0.y,a0.z,a0.w,a1.x,a1.y,a1.z,a1.w,
                         a2.x,a2.y,a2.z,a2.w,a3.x,a3.y,a3.z,a3.w};
#pragma unroll
        for (int s=0;s<16;s++) A[s] = -__expf(tmp[s]);
        bool structured = a_structured(A);
        float A0 = A[0];
#pragma unroll
        for (int s=0;s<16;s++)
            h[s] = hstart[((size_t)((b*NCH + c)*16 + s))*DI + d];
        float Dd = Dp[d];
        __syncthreads();
        for (int t0 = 0; t0 < CSZ; t0 += 8){
            float dl[8], uu[8], zz[8];
#pragma unroll
            for (int k=0;k<8;k++){
                size_t m = (size_t)(mbase+t0+k);
                dl[k] = xdc[m*XDW + d];
                uu[k] = bf2f(xcB[m*DI + d]);
                zz[k] = bf2f(zB[m*DI + d]);
            }
            if (structured) {
#pragma unroll
                for (int k=0;k<8;k++){
                    int t = t0+k;
                    float dlt = dl[k];
                    float u = uu[k];
                    float du = dlt*u;
                    float pk[16];
                    pk_ladder(__expf(dlt*A0), pk);
                    float y0=0.f, y1=0.f, y2=0.f, y3=0.f;
#pragma unroll
                    for (int s=0;s<16;s+=4){
                        h[s]   = pk[s]*h[s]     + du*Bs[t*16+s];   y0 += h[s]*Cs[t*16+s];
                        h[s+1] = pk[s+1]*h[s+1] + du*Bs[t*16+s+1]; y1 += h[s+1]*Cs[t*16+s+1];
                        h[s+2] = pk[s+2]*h[s+2] + du*Bs[t*16+s+2]; y2 += h[s+2]*Cs[t*16+s+2];
                        h[s+3] = pk[s+3]*h[s+3] + du*Bs[t*16+s+3]; y3 += h[s+3]*Cs[t*16+s+3];
                    }
                    float y = (y0+y1)+(y2+y3);
                    yB[t*YS+d] = f2bf((y + u*Dd) * silu_f(zz[k]));
                }
            } else {
#pragma unroll
                for (int k=0;k<8;k++){
                    int t = t0+k;
                    float dlt = dl[k];
                    float u = uu[k];
                    float du = dlt*u;
                    float y0=0.f, y1=0.f, y2=0.f, y3=0.f;
#pragma unroll
                    for (int s=0;s<16;s+=4){
                        h[s]   = __expf(dlt*A[s])*h[s]     + du*Bs[t*16+s];   y0 += h[s]*Cs[t*16+s];
                        h[s+1] = __expf(dlt*A[s+1])*h[s+1] + du*Bs[t*16+s+1]; y1 += h[s+1]*Cs[t*16+s+1];
                        h[s+2] = __expf(dlt*A[s+2])*h[s+2] + du*Bs[t*16+s+2]; y2 += h[s+2]*Cs[t*16+s+2];
                        h[s+3] = __expf(dlt*A[s+3])*h[s+3] + du*Bs[t*16+s+3]; y3 += h[s+3]*Cs[t*16+s+3];
                    }
                    float y = (y0+y1)+(y2+y3);
                    yB[t*YS+d] = f2bf((y + u*Dd) * silu_f(zz[k]));
                }
            }
        }
    }
    __syncthreads();   // yB done; Bs/Cs dead -> region2 reusable as oB
    // ---- Phase B
    int wave = tid>>6, lane = tid&63;
    int r = lane&15, g = lane>>4;
    // Stage 1: o[32][128] = y @ oW^T  (K=256)
    {
        f32x4 s1[2][2];
#pragma unroll
        for (int i=0;i<2;i++)
#pragma unroll
            for (int j=0;j<2;j++) s1[i][j] = (f32x4){0.f,0.f,0.f,0.f};
#pragma unroll
        for (int ks=0;ks<8;ks++){
            short8 ya[2];
#pragma unroll
            for (int i=0;i<2;i++)
                ya[i] = *(const short8*)&yB[(i*16+r)*YS + ks*32 + g*8];
            short8 wh_[2], wl_[2];
#pragma unroll
            for (int j=0;j<2;j++){
                size_t wa = (size_t)(wave*32 + j*16 + r)*256 + ks*32 + g*8;
                wh_[j] = *(const short8*)&oWh[wa];
                wl_[j] = *(const short8*)&oWl[wa];
            }
#pragma unroll
            for (int i=0;i<2;i++)
#pragma unroll
            for (int j=0;j<2;j++){
                s1[i][j] = MFMA16(ya[i], wh_[j], s1[i][j]);
                s1[i][j] = MFMA16(ya[i], wl_[j], s1[i][j]);
            }
        }
#pragma unroll
        for (int i=0;i<2;i++)
#pragma unroll
        for (int j=0;j<2;j++)
#pragma unroll
        for (int q=0;q<4;q++){
            int t = i*16 + g*4 + q;
            int n = wave*32 + j*16 + r;
            oB[t*OS+n] = f2bf(s1[i][j][q]);
        }
    }
    __syncthreads();   // oB ready; yB reads done
    // Stage 2: f[32][256] = gelu(o @ w1^T + b1)  (K=128), into yB
    {
        f32x4 s2[2][4];
#pragma unroll
        for (int i=0;i<2;i++)
#pragma unroll
            for (int j=0;j<4;j++) s2[i][j] = (f32x4){0.f,0.f,0.f,0.f};
#pragma unroll
        for (int ks=0;ks<4;ks++){
            short8 oa[2];
#pragma unroll
            for (int i=0;i<2;i++)
                oa[i] = *(const short8*)&oB[(i*16+r)*OS + ks*32 + g*8];
            short8 wh_[4], wl_[4];
#pragma unroll
            for (int j=0;j<4;j++){
                size_t wa = (size_t)(wave*64 + j*16 + r)*128 + ks*32 + g*8;
                wh_[j] = *(const short8*)&w1h[wa];
                wl_[j] = *(const short8*)&w1l[wa];
            }
#pragma unroll
            for (int i=0;i<2;i++)
#pragma unroll
            for (int j=0;j<4;j++){
                s2[i][j] = MFMA16(oa[i], wh_[j], s2[i][j]);
                s2[i][j] = MFMA16(oa[i], wl_[j], s2[i][j]);
            }
        }
#pragma unroll
        for (int i=0;i<2;i++)
#pragma unroll
        for (int j=0;j<4;j++)
#pragma unroll
        for (int q=0;q<4;q++){
            int t = i*16 + g*4 + q;
            int n = wave*64 + j*16 + r;
            yB[t*YS+n] = f2bf(gelu_f(s2[i][j][q] + b1[n]));
        }
    }
    __syncthreads();   // f (in yB) done
    // Stage 3: hnew[32][128] = f @ w2^T + b2  (K=256) -> global plane
    {
        f32x4 s3[2][2];
#pragma unroll
        for (int i=0;i<2;i++)
#pragma unroll
            for (int j=0;j<2;j++) s3[i][j] = (f32x4){0.f,0.f,0.f,0.f};
#pragma unroll
        for (int ks=0;ks<8;ks++){
            short8 fa[2];
#pragma unroll
            for (int i=0;i<2;i++)
                fa[i] = *(const short8*)&yB[(i*16+r)*YS + ks*32 + g*8];
            short8 wh_[2], wl_[2];
#pragma unroll
            for (int j=0;j<2;j++){
                size_t wa = (size_t)(wave*32 + j*16 + r)*256 + ks*32 + g*8;
                wh_[j] = *(const short8*)&w2h[wa];
                wl_[j] = *(const short8*)&w2l[wa];
            }
#pragma unroll
            for (int i=0;i<2;i++)
#pragma unroll
            for (int j=0;j<2;j++){
                s3[i][j] = MFMA16(fa[i], wh_[j], s3[i][j]);
                s3[i][j] = MFMA16(fa[i], wl_[j], s3[i][j]);
            }
        }
#pragma unroll
        for (int i=0;i<2;i++)
#pragma unroll
        for (int j=0;j<2;j++)
#pragma unroll
        for (int q=0;q<4;q++){
            int t = i*16 + g*4 + q;
            int n = wave*32 + j*16 + r;
            hB[(size_t)(mbase + t)*DM + n] = f2bf(s3[i][j][q] + b2[n]);
        }
    }
}

// ---------------------------------------------------------------------------
// Final transpose: out[bv, d, n] = h[bv*1024+n, d]
__global__ __launch_bounds__(256) void final_transpose(
    const ushort_t* __restrict__ hB, float* __restrict__ out)
{
    int n0 = blockIdx.x*32, d0 = blockIdx.y*32, bv = blockIdx.z;
    __shared__ float ts[32][33];
    int tid = threadIdx.x;
    int c = tid & 31, r0 = tid >> 5;
    for (int rr = r0; rr < 32; rr += 8)
        ts[rr][c] = bf2f(hB[(size_t)(bv*TSEQ + n0 + rr)*DM + d0 + c]);
    __syncthreads();
    for (int rr = r0; rr < 32; rr += 8)
        out[(size_t)(bv*DM + d0 + rr)*TSEQ + n0 + c] = ts[c][rr];
}

// ---------------------------------------------------------------------------
extern "C" void kernel_launch(void* const* d_in, const int* in_sizes, int n_in,
                              void* d_out, int out_size, void* d_ws, size_t ws_size,
                              hipStream_t stream)
{
    const float* x     = (const float*)d_in[0];
    const float* Wp    = (const float*)d_in[1];
    const float* Wpb   = (const float*)d_in[2];
    const float* inW   = (const float*)d_in[3];
    const float* convW = (const float*)d_in[4];
    const float* convB = (const float*)d_in[5];
    const float* xpW   = (const float*)d_in[6];
    const float* dtW   = (const float*)d_in[7];
    const float* dtB   = (const float*)d_in[8];
    const float* Alog  = (const float*)d_in[9];
    const float* Dp    = (const float*)d_in[10];
    const float* outW  = (const float*)d_in[11];
    const float* l1W   = (const float*)d_in[12];
    const float* l1B   = (const float*)d_in[13];
    const float* l2W   = (const float*)d_in[14];
    const float* l2B   = (const float*)d_in[15];
    float* out = (float*)d_out;

    char* base = (char*)d_ws;
    size_t off = 0;
    auto alloc = [&](size_t bytes) { char* p = base + off; off += (bytes + 255) & ~(size_t)255; return p; };

    const size_t P128 = (size_t)MTOK*DM*2;     // [M][128] bf16 plane
    const size_t P256 = (size_t)MTOK*DI*2;     // [M][256] bf16 plane

    ushort_t* hB  = (ushort_t*)alloc(P128);
    // slab1: xin plane (16.8MB) UNION xdc fp32 (37.75MB)
    char* slab1 = alloc((size_t)MTOK*XDW*4);
    ushort_t* xinB = (ushort_t*)slab1;
    float*    xdc  = (float*)slab1;
    ushort_t* zB  = (ushort_t*)alloc(P256);
    ushort_t* xcB = (ushort_t*)alloc(P256);
    float* hloc   = (float*)alloc((size_t)BSEQ*NCH*DS*DI*4);
    float* hstart = (float*)alloc((size_t)BSEQ*NCH*DS*DI*4);
    float* sd     = (float*)alloc((size_t)BSEQ*NCH*DI*4);
    ushort_t* inWh  = (ushort_t*)alloc((size_t)512*128*2);
    ushort_t* inWl  = (ushort_t*)alloc((size_t)512*128*2);
    ushort_t* wcH   = (ushort_t*)alloc((size_t)XDWP*256*2);
    ushort_t* wcL   = (ushort_t*)alloc((size_t)XDWP*256*2);
    ushort_t* outWh = (ushort_t*)alloc((size_t)128*256*2);
    ushort_t* outWl = (ushort_t*)alloc((size_t)128*256*2);
    ushort_t* l1Wh  = (ushort_t*)alloc((size_t)256*128*2);
    ushort_t* l1Wl  = (ushort_t*)alloc((size_t)256*128*2);
    ushort_t* l2Wh  = (ushort_t*)alloc((size_t)128*256*2);
    ushort_t* l2Wl  = (ushort_t*)alloc((size_t)128*256*2);

    patch_embed<<<dim3(32,16), 256, 0, stream>>>(x, Wp, Wpb, hB);

    for (int L = 0; L < L_LAYERS; L++) {
        const float* inW_l   = inW   + (size_t)L*2*DI*DM;
        const float* convW_l = convW + (size_t)L*DI*4;
        const float* convB_l = convB + (size_t)L*DI;
        const float* xpW_l   = xpW   + (size_t)L*(DTR+2*DS)*DI;
        const float* dtW_l   = dtW   + (size_t)L*DI*DTR;
        const float* dtB_l   = dtB   + (size_t)L*DI;
        const float* Alog_l  = Alog  + (size_t)L*DI*DS;
        const float* Dp_l    = Dp    + (size_t)L*DI;
        const float* outW_l  = outW  + (size_t)L*DM*DI;
        const float* l1W_l   = l1W   + (size_t)L*DFF*DM;
        const float* l1B_l   = l1B   + (size_t)L*DFF;
        const float* l2W_l   = l2W   + (size_t)L*DM*DFF;
        const float* l2B_l   = l2B   + (size_t)L*DM;

        // ---- weight prep (weights stay split hi/lo)
        prep_split<<<(512*128+255)/256, 256, 0, stream>>>(inW_l, inWh, inWl, 512*128);
        prep_wcomb<<<XDWP, 256, 0, stream>>>(xpW_l, dtW_l, wcH, wcL);
        prep_split<<<(128*256+255)/256, 256, 0, stream>>>(outW_l, outWh, outWl, 128*256);
        prep_split<<<(256*128+255)/256, 256, 0, stream>>>(l1W_l, l1Wh, l1Wl, 256*128);
        prep_split<<<(128*256+255)/256, 256, 0, stream>>>(l2W_l, l2Wh, l2Wl, 128*256);

        // ---- in_proj: [M,512] = h @ inW^T, K=128; routes cols to xin / z
        gemm_stream<128,64,EPI_SPLIT2><<<dim3(MTOK/256, 8), 256, 0, stream>>>(
            hB, inWh, inWl, nullptr, xinB, zB, nullptr);
        // ---- conv + silu
        conv_silu<<<dim3(BSEQ, DI/64, TSEQ/64), 256, 0, stream>>>(
            xinB, convW_l, convB_l, xcB);
        // ---- delta|B|C GEMM: [M,288] = xc @ wc^T, K=256 (softplus on delta)
        // 9 y-tiles: n0 = 0..256 (the n0=288 tile is all pad -> skipped)
        gemm_stream<256,32,EPI_DELTA><<<dim3(MTOK/256, 9), 256, 0, stream>>>(
            xcB, wcH, wcL, dtB_l, nullptr, nullptr, xdc);
        // ---- chunked scan
        scan_pass1<<<dim3(BSEQ, NCH), 256, 0, stream>>>(
            xdc, xcB, Alog_l, hloc, sd);
        scan_combine<<<dim3(BSEQ, DS), 256, 0, stream>>>(
            hloc, sd, Alog_l, hstart);
        // ---- fused scan pass2 + out_proj + FFN
        scan_fused<<<dim3(BSEQ, NCH), 256, 0, stream>>>(
            xdc, xcB, zB, Alog_l, Dp_l, hstart,
            outWh, outWl, l1Wh, l1Wl, l1B_l, l2Wh, l2Wl, l2B_l, hB);
    }

    final_transpose<<<dim3(TSEQ/32, DM/32, BSEQ), 256, 0, stream>>>(hB, out);
}

// Round 12
// 500.305 us; speedup vs baseline: 1.1310x; 1.0382x over previous
//
#include <hip/hip_runtime.h>
#include <math.h>

// Problem constants
#define L_LAYERS 2
#define DM   128
#define DI   256
#define DS   16
#define DTR  8
#define DFF  256
#define PLEN 16
#define BSEQ 32
#define TSEQ 1024
#define MTOK (BSEQ*TSEQ)   // 32768
#define NCH  32            // scan chunks
#define CSZ  32            // TSEQ/NCH
#define XDW  288           // delta(256) | B(16) | C(16)
#define XDWP 320           // padded rows for delta weight

#define EPI_SPLIT2 0
#define EPI_DELTA  3

typedef unsigned short ushort_t;
typedef __attribute__((ext_vector_type(8))) short short8;
typedef __attribute__((ext_vector_type(4))) float f32x4;
#define MFMA16(a,b,c) __builtin_amdgcn_mfma_f32_16x16x32_bf16(a,b,c,0,0,0)

__device__ __forceinline__ float silu_f(float x){ return x / (1.f + __expf(-x)); }
__device__ __forceinline__ float gelu_f(float x){ return 0.5f*x*(1.f + erff(x*0.7071067811865475f)); }
__device__ __forceinline__ float softplus_f(float x){ return (x > 20.f) ? x : log1pf(__expf(x)); }

__device__ __forceinline__ ushort_t f2bf(float f){
    unsigned int u = __float_as_uint(f);
    u += 0x7fffu + ((u >> 16) & 1u);
    return (ushort_t)(u >> 16);
}
__device__ __forceinline__ float bf2f(ushort_t h){
    return __uint_as_float(((unsigned int)h) << 16);
}

// Check A[s] ~= A[0]*(s+1) (true for the reference A_log = log(1..16) tiled).
__device__ __forceinline__ bool a_structured(const float* A){
    bool ok = (A[0] < 0.f);
#pragma unroll
    for (int s=1;s<16;s++){
        float r = A[s]/A[0];
        ok = ok && (fabsf(r - (float)(s+1)) <= 1e-3f);
    }
    return ok;
}

// pk[s] = p^(s+1), log-depth multiply ladder (registers only)
__device__ __forceinline__ void pk_ladder(float p, float* pk){
    float p2 = p*p;
    float p3 = p2*p;
    float p4 = p2*p2;
    float p5 = p4*p, p6 = p4*p2, p7 = p4*p3, p8 = p4*p4;
    pk[0]=p;  pk[1]=p2; pk[2]=p3; pk[3]=p4;
    pk[4]=p5; pk[5]=p6; pk[6]=p7; pk[7]=p8;
    pk[8]=p8*p;  pk[9]=p8*p2;  pk[10]=p8*p3;  pk[11]=p8*p4;
    pk[12]=p8*p5; pk[13]=p8*p6; pk[14]=p8*p7; pk[15]=p8*p8;
}

// ---------------------------------------------------------------------------
// Patch embedding -> h (single bf16 plane)
__global__ __launch_bounds__(256) void patch_embed(
    const float* __restrict__ x, const float* __restrict__ Wp,
    const float* __restrict__ bp, ushort_t* __restrict__ hB)
{
    int bv = blockIdx.x, n0 = blockIdx.y * 64;
    __shared__ float xs[PLEN][64];
    __shared__ float ws[PLEN][DM];
    __shared__ float bs[DM];
    int tid = threadIdx.x;
    {
        int c = tid & 63, r0 = tid >> 6;
        for (int p = r0; p < PLEN; p += 4)
            xs[p][c] = x[bv*(PLEN*TSEQ) + p*TSEQ + n0 + c];
    }
    for (int i = tid; i < DM*PLEN; i += 256) {
        int d = i >> 4, p = i & 15;
        ws[p][d] = Wp[i];
    }
    if (tid < DM) bs[tid] = bp[tid];
    __syncthreads();
    int tm = tid & 15;
    int tn = tid >> 4;
    float acc[4][8];
#pragma unroll
    for (int i=0;i<4;i++)
#pragma unroll
        for (int j=0;j<8;j++) acc[i][j] = bs[tn*8+j];
#pragma unroll
    for (int p=0;p<PLEN;p++) {
        float4 a = *(const float4*)&xs[p][tm*4];
        float4 w0 = *(const float4*)&ws[p][tn*8];
        float4 w1 = *(const float4*)&ws[p][tn*8+4];
        const float* ap = (const float*)&a;
        const float* wp0 = (const float*)&w0;
        const float* wp1 = (const float*)&w1;
#pragma unroll
        for (int i=0;i<4;i++){
#pragma unroll
            for (int j=0;j<4;j++){
                acc[i][j]   += ap[i]*wp0[j];
                acc[i][j+4] += ap[i]*wp1[j];
            }
        }
    }
#pragma unroll
    for (int i=0;i<4;i++){
        size_t row = (size_t)(bv*TSEQ + n0 + tm*4 + i)*DM + tn*8;
        short8 hv;
#pragma unroll
        for (int j=0;j<8;j++) hv[j] = (short)f2bf(acc[i][j]);
        *(short8*)&hB[row] = hv;
    }
}

// ---------------------------------------------------------------------------
// One-dispatch per-layer weight prep: fp32 -> bf16 hi/lo planes for
// inW (65536) | combined x_proj 320x256 (81920) | outW (32768) |
// l1W (32768) | l2W (32768). Total 245760 elements.
#define PREP_ELEMS 245760
__global__ __launch_bounds__(256) void prep_layer(
    const float* __restrict__ inW, const float* __restrict__ xpW,
    const float* __restrict__ dtW, const float* __restrict__ outW,
    const float* __restrict__ l1W, const float* __restrict__ l2W,
    ushort_t* __restrict__ inWh, ushort_t* __restrict__ inWl,
    ushort_t* __restrict__ wcH,  ushort_t* __restrict__ wcL,
    ushort_t* __restrict__ outWh,ushort_t* __restrict__ outWl,
    ushort_t* __restrict__ l1Wh, ushort_t* __restrict__ l1Wl,
    ushort_t* __restrict__ l2Wh, ushort_t* __restrict__ l2Wl)
{
    int e = blockIdx.x*256 + threadIdx.x;
    if (e >= PREP_ELEMS) return;
    float v; ushort_t *dh, *dl; int o;
    if (e < 65536){
        v = inW[e]; dh = inWh; dl = inWl; o = e;
    } else if (e < 147456){
        int ee = e - 65536;           // 0..81919
        int n = ee >> 8, k = ee & 255;
        if (n < 256){
            v = 0.f;
#pragma unroll
            for (int r=0;r<8;r++) v += dtW[n*8+r]*xpW[r*256+k];
        } else if (n < XDW){
            v = xpW[(n-256+DTR)*256 + k];
        } else {
            v = 0.f;
        }
        dh = wcH; dl = wcL; o = ee;
    } else if (e < 180224){
        int ee = e - 147456; v = outW[ee]; dh = outWh; dl = outWl; o = ee;
    } else if (e < 212992){
        int ee = e - 180224; v = l1W[ee]; dh = l1Wh; dl = l1Wl; o = ee;
    } else {
        int ee = e - 212992; v = l2W[ee]; dh = l2Wh; dl = l2Wl; o = ee;
    }
    ushort_t hi = f2bf(v);
    dh[o] = hi;
    dl[o] = f2bf(v - bf2f(hi));
}

// ---------------------------------------------------------------------------
// Streaming MFMA GEMM: C[M,*] = A[M,KT] @ W[*,KT]^T
// A single bf16 plane; W split hi/lo (2-term). Weights cached in LDS once
// (XOR-swizzled); K-loop barrier-free; A streamed from global (L3-resident).
template<int KT, int NT, int EPI>
__global__ __launch_bounds__(256) void gemm_stream(
    const ushort_t* __restrict__ A,
    const ushort_t* __restrict__ WH, const ushort_t* __restrict__ WL,
    const float* __restrict__ bias,
    ushort_t* __restrict__ o1, ushort_t* __restrict__ o2,
    float* __restrict__ CF)
{
    constexpr int NCHK = KT/8;
    constexpr int NF = NT/16;
    __shared__ ushort_t sWh[NT*KT];
    __shared__ ushort_t sWl[NT*KT];
    int m0 = blockIdx.x*256, n0 = blockIdx.y*NT;
    int tid = threadIdx.x;
    for (int i = tid; i < NT*NCHK; i += 256) {
        int nrow = i / NCHK, c = i % NCHK;
        int cs = c ^ (nrow & 7);
        *(short8*)&sWh[nrow*KT + cs*8] = *(const short8*)&WH[(size_t)(n0+nrow)*KT + c*8];
        *(short8*)&sWl[nrow*KT + cs*8] = *(const short8*)&WL[(size_t)(n0+nrow)*KT + c*8];
    }
    __syncthreads();
    int wave = tid>>6, lane = tid&63;
    int r = lane&15, g = lane>>4;
    int mw = m0 + wave*64;
    f32x4 acc[4][NF];
#pragma unroll
    for (int i=0;i<4;i++)
#pragma unroll
        for (int j=0;j<NF;j++) acc[i][j] = (f32x4){0.f,0.f,0.f,0.f};

#pragma unroll
    for (int ks = 0; ks < KT/32; ks++){
        short8 ah[4];
#pragma unroll
        for (int i=0;i<4;i++){
            size_t ga = (size_t)(mw + i*16 + r)*KT + ks*32 + g*8;
            ah[i] = *(const short8*)&A[ga];
        }
        short8 wh[NF], wl[NF];
#pragma unroll
        for (int j=0;j<NF;j++){
            int nrow = j*16 + r;
            int cs = (ks*4 + g) ^ (nrow & 7);
            wh[j] = *(const short8*)&sWh[nrow*KT + cs*8];
            wl[j] = *(const short8*)&sWl[nrow*KT + cs*8];
        }
#pragma unroll
        for (int i=0;i<4;i++)
#pragma unroll
        for (int j=0;j<NF;j++){
            acc[i][j] = MFMA16(ah[i], wh[j], acc[i][j]);
            acc[i][j] = MFMA16(ah[i], wl[j], acc[i][j]);
        }
    }
#pragma unroll
    for (int i=0;i<4;i++){
#pragma unroll
        for (int j=0;j<NF;j++){
            int nn = n0 + j*16 + r;
#pragma unroll
            for (int q=0;q<4;q++){
                int mm = mw + i*16 + g*4 + q;
                float v = acc[i][j][q];
                if (EPI == EPI_DELTA){
                    if (nn < XDW){
                        if (nn < 256) v = softplus_f(v + bias[nn]);
                        CF[(size_t)mm*XDW + nn] = v;
                    }
                } else {
                    ushort_t hv = f2bf(v);
                    if (nn < 256) o1[(size_t)mm*256 + nn] = hv;
                    else          o2[(size_t)mm*256 + nn-256] = hv;
                }
            }
        }
    }
}

// ---------------------------------------------------------------------------
// Causal depthwise conv (width 4) + bias + SiLU; single bf16 plane in/out
__global__ __launch_bounds__(256) void conv_silu(
    const ushort_t* __restrict__ xB, const float* __restrict__ cw,
    const float* __restrict__ cb, ushort_t* __restrict__ oB)
{
    int b = blockIdx.x, c0 = blockIdx.y*64, t0 = blockIdx.z*64;
    __shared__ float xin_s[67][64];
    __shared__ float cws[64][5];
    __shared__ float cbs[64];
    int tid = threadIdx.x;
    { int c = tid >> 2, k = tid & 3; cws[c][k] = cw[(c0+c)*4 + k]; }
    if (tid < 64) cbs[tid] = cb[c0+tid];
    {
        int c = tid & 63, r0 = tid >> 6;
        for (int rr = r0; rr < 67; rr += 4) {
            int t = t0 - 3 + rr;
            xin_s[rr][c] = (t >= 0) ? bf2f(xB[(size_t)(b*TSEQ + t)*DI + c0 + c]) : 0.f;
        }
    }
    __syncthreads();
#pragma unroll
    for (int p = 0; p < 16; p++) {
        int idx = p*256 + tid;
        int tl = idx >> 6, cl = idx & 63;
        float v = cbs[cl];
#pragma unroll
        for (int k=0;k<4;k++) v += cws[cl][k]*xin_s[tl+k][cl];
        oB[(size_t)(b*TSEQ + t0 + tl)*DI + c0 + cl] = f2bf(silu_f(v));
    }
}

// ---------------------------------------------------------------------------
// Scan pass 1: per (b, chunk, d): local end-state (h_start=0) and sum(delta)
// 8-deep load prefetch per group.
__global__ __launch_bounds__(256) void scan_pass1(
    const float* __restrict__ xdc, const ushort_t* __restrict__ xcB,
    const float* __restrict__ Alog,
    float* __restrict__ hloc, float* __restrict__ sd)
{
    int b = blockIdx.x, c = blockIdx.y;
    int d = threadIdx.x;
    __shared__ float Bs[CSZ][16];
    int mbase = b*TSEQ + c*CSZ;
    for (int i = d; i < CSZ*16; i += 256) {
        int t = i >> 4, s = i & 15;
        Bs[t][s] = xdc[(size_t)(mbase+t)*XDW + 256 + s];
    }
    float A[16], h[16];
    {
        float4 a0 = *(const float4*)&Alog[d*16];
        float4 a1 = *(const float4*)&Alog[d*16+4];
        float4 a2 = *(const float4*)&Alog[d*16+8];
        float4 a3 = *(const float4*)&Alog[d*16+12];
        float tmp[16] = {a0.x,a0.y,a0.z,a0.w,a1.x,a1.y,a1.z,a1.w,
                         a2.x,a2.y,a2.z,a2.w,a3.x,a3.y,a3.z,a3.w};
#pragma unroll
        for (int s=0;s<16;s++){ A[s] = -__expf(tmp[s]); h[s] = 0.f; }
    }
    bool structured = a_structured(A);
    float A0 = A[0];
    float sdv = 0.f;
    __syncthreads();
    for (int t0 = 0; t0 < CSZ; t0 += 8){
        float dl[8], uu[8];
#pragma unroll
        for (int k=0;k<8;k++){
            size_t m = (size_t)(mbase+t0+k);
            dl[k] = xdc[m*XDW + d];
            uu[k] = bf2f(xcB[m*DI + d]);
        }
        if (structured) {
#pragma unroll
            for (int k=0;k<8;k++){
                int t = t0+k;
                float dlt = dl[k];
                sdv += dlt;
                float du = dlt*uu[k];
                float pk[16];
                pk_ladder(__expf(dlt*A0), pk);
#pragma unroll
                for (int s=0;s<16;s++)
                    h[s] = pk[s]*h[s] + du*Bs[t][s];
            }
        } else {
#pragma unroll
            for (int k=0;k<8;k++){
                int t = t0+k;
                float dlt = dl[k];
                sdv += dlt;
                float du = dlt*uu[k];
#pragma unroll
                for (int s=0;s<16;s++)
                    h[s] = __expf(dlt*A[s])*h[s] + du*Bs[t][s];
            }
        }
    }
#pragma unroll
    for (int s=0;s<16;s++)
        hloc[((size_t)((b*NCH + c)*16 + s))*DI + d] = h[s];
    sd[(b*NCH + c)*DI + d] = sdv;
}

// ---------------------------------------------------------------------------
// Prefix-combine over chunks (thread = (b,s,d))
__global__ __launch_bounds__(256) void scan_combine(
    const float* __restrict__ hloc, const float* __restrict__ sd,
    const float* __restrict__ Alog, float* __restrict__ hstart)
{
    int b = blockIdx.x, s = blockIdx.y;
    int d = threadIdx.x;
    float A = -__expf(Alog[d*16+s]);
    float hs = 0.f;
    for (int c = 0; c < NCH; c++){
        size_t base = ((size_t)((b*NCH + c)*16 + s))*DI + d;
        hstart[base] = hs;
        float sdp = sd[(b*NCH + c)*DI + d];
        hs = __expf(sdp*A)*hs + hloc[base];
    }
}

// ---------------------------------------------------------------------------
// Fused scan pass 2 + out_proj + FFN (gelu) for a 32-token chunk.
// Single-plane activations; Phase A uses 8-deep load prefetch.
// LDS: yB [32][264] bf16 (16896 B);
// region2 = union( oB [32][136] bf16 (8704 B), Bs/Cs fp32 (4096 B) ).
// Total 25600 B.
__global__ __launch_bounds__(256,3) void scan_fused(
    const float* __restrict__ xdc,
    const ushort_t* __restrict__ xcB, const ushort_t* __restrict__ zB,
    const float* __restrict__ Alog, const float* __restrict__ Dp,
    const float* __restrict__ hstart,
    const ushort_t* __restrict__ oWh, const ushort_t* __restrict__ oWl,
    const ushort_t* __restrict__ w1h, const ushort_t* __restrict__ w1l,
    const float* __restrict__ b1,
    const ushort_t* __restrict__ w2h, const ushort_t* __restrict__ w2l,
    const float* __restrict__ b2,
    ushort_t* __restrict__ hB)
{
    constexpr int YS = DI + 8;    // 264 shorts (row stride 528 B, 16-aligned)
    constexpr int OS = DM + 8;    // 136 shorts
    __shared__ __align__(16) ushort_t smem[CSZ*YS + CSZ*OS];   // 25600 B
    ushort_t* yB = smem;                      // [t*YS + d]
    ushort_t* oB = smem + CSZ*YS;             // [t*OS + n]
    float*    Bs = (float*)(smem + CSZ*YS);   // union with oB
    float*    Cs = Bs + CSZ*16;

    int b = blockIdx.x, c = blockIdx.y;
    int tid = threadIdx.x;
    int mbase = b*TSEQ + c*CSZ;
    for (int i = tid; i < CSZ*32; i += 256) {
        int t = i >> 5, s2 = i & 31;
        float v = xdc[(size_t)(mbase+t)*XDW + 256 + s2];
        if (s2 < 16) Bs[t*16+s2] = v; else Cs[t*16+s2-16] = v;
    }
    // ---- Phase A: scan
    {
        int d = tid;
        float A[16], h[16];
        float4 a0 = *(const float4*)&Alog[d*16];
        float4 a1 = *(const float4*)&Alog[d*16+4];
        float4 a2 = *(const float4*)&Alog[d*16+8];
        float4 a3 = *(const float4*)&Alog[d*16+12];
        float tmp[16] = {a0.x,a0.y,a0.z,a0.w,a1.x,a1.y,a1.z,a1.w,
                         a2.x,a2.y,a2.z,a2.w,a3.x,a3.y,a3.z,a3.w};
#pragma unroll
        for (int s=0;s<16;s++) A[s] = -__expf(tmp[s]);
        bool structured = a_structured(A);
        float A0 = A[0];
#pragma unroll
        for (int s=0;s<16;s++)
            h[s] = hstart[((size_t)((b*NCH + c)*16 + s))*DI + d];
        float Dd = Dp[d];
        __syncthreads();
        for (int t0 = 0; t0 < CSZ; t0 += 8){
            float dl[8], uu[8], zz[8];
#pragma unroll
            for (int k=0;k<8;k++){
                size_t m = (size_t)(mbase+t0+k);
                dl[k] = xdc[m*XDW + d];
                uu[k] = bf2f(xcB[m*DI + d]);
                zz[k] = bf2f(zB[m*DI + d]);
            }
            if (structured) {
#pragma unroll
                for (int k=0;k<8;k++){
                    int t = t0+k;
                    float dlt = dl[k];
                    float u = uu[k];
                    float du = dlt*u;
                    float pk[16];
                    pk_ladder(__expf(dlt*A0), pk);
                    float y0=0.f, y1=0.f, y2=0.f, y3=0.f;
#pragma unroll
                    for (int s=0;s<16;s+=4){
                        h[s]   = pk[s]*h[s]     + du*Bs[t*16+s];   y0 += h[s]*Cs[t*16+s];
                        h[s+1] = pk[s+1]*h[s+1] + du*Bs[t*16+s+1]; y1 += h[s+1]*Cs[t*16+s+1];
                        h[s+2] = pk[s+2]*h[s+2] + du*Bs[t*16+s+2]; y2 += h[s+2]*Cs[t*16+s+2];
                        h[s+3] = pk[s+3]*h[s+3] + du*Bs[t*16+s+3]; y3 += h[s+3]*Cs[t*16+s+3];
                    }
                    float y = (y0+y1)+(y2+y3);
                    yB[t*YS+d] = f2bf((y + u*Dd) * silu_f(zz[k]));
                }
            } else {
#pragma unroll
                for (int k=0;k<8;k++){
                    int t = t0+k;
                    float dlt = dl[k];
                    float u = uu[k];
                    float du = dlt*u;
                    float y0=0.f, y1=0.f, y2=0.f, y3=0.f;
#pragma unroll
                    for (int s=0;s<16;s+=4){
                        h[s]   = __expf(dlt*A[s])*h[s]     + du*Bs[t*16+s];   y0 += h[s]*Cs[t*16+s];
                        h[s+1] = __expf(dlt*A[s+1])*h[s+1] + du*Bs[t*16+s+1]; y1 += h[s+1]*Cs[t*16+s+1];
                        h[s+2] = __expf(dlt*A[s+2])*h[s+2] + du*Bs[t*16+s+2]; y2 += h[s+2]*Cs[t*16+s+2];
                        h[s+3] = __expf(dlt*A[s+3])*h[s+3] + du*Bs[t*16+s+3]; y3 += h[s+3]*Cs[t*16+s+3];
                    }
                    float y = (y0+y1)+(y2+y3);
                    yB[t*YS+d] = f2bf((y + u*Dd) * silu_f(zz[k]));
                }
            }
        }
    }
    __syncthreads();   // yB done; Bs/Cs dead -> region2 reusable as oB
    // ---- Phase B
    int wave = tid>>6, lane = tid&63;
    int r = lane&15, g = lane>>4;
    // Stage 1: o[32][128] = y @ oW^T  (K=256)
    {
        f32x4 s1[2][2];
#pragma unroll
        for (int i=0;i<2;i++)
#pragma unroll
            for (int j=0;j<2;j++) s1[i][j] = (f32x4){0.f,0.f,0.f,0.f};
#pragma unroll
        for (int ks=0;ks<8;ks++){
            short8 ya[2];
#pragma unroll
            for (int i=0;i<2;i++)
                ya[i] = *(const short8*)&yB[(i*16+r)*YS + ks*32 + g*8];
            short8 wh_[2], wl_[2];
#pragma unroll
            for (int j=0;j<2;j++){
                size_t wa = (size_t)(wave*32 + j*16 + r)*256 + ks*32 + g*8;
                wh_[j] = *(const short8*)&oWh[wa];
                wl_[j] = *(const short8*)&oWl[wa];
            }
#pragma unroll
            for (int i=0;i<2;i++)
#pragma unroll
            for (int j=0;j<2;j++){
                s1[i][j] = MFMA16(ya[i], wh_[j], s1[i][j]);
                s1[i][j] = MFMA16(ya[i], wl_[j], s1[i][j]);
            }
        }
#pragma unroll
        for (int i=0;i<2;i++)
#pragma unroll
        for (int j=0;j<2;j++)
#pragma unroll
        for (int q=0;q<4;q++){
            int t = i*16 + g*4 + q;
            int n = wave*32 + j*16 + r;
            oB[t*OS+n] = f2bf(s1[i][j][q]);
        }
    }
    __syncthreads();   // oB ready; yB reads done
    // Stage 2: f[32][256] = gelu(o @ w1^T + b1)  (K=128), into yB
    {
        f32x4 s2[2][4];
#pragma unroll
        for (int i=0;i<2;i++)
#pragma unroll
            for (int j=0;j<4;j++) s2[i][j] = (f32x4){0.f,0.f,0.f,0.f};
#pragma unroll
        for (int ks=0;ks<4;ks++){
            short8 oa[2];
#pragma unroll
            for (int i=0;i<2;i++)
                oa[i] = *(const short8*)&oB[(i*16+r)*OS + ks*32 + g*8];
            short8 wh_[4], wl_[4];
#pragma unroll
            for (int j=0;j<4;j++){
                size_t wa = (size_t)(wave*64 + j*16 + r)*128 + ks*32 + g*8;
                wh_[j] = *(const short8*)&w1h[wa];
                wl_[j] = *(const short8*)&w1l[wa];
            }
#pragma unroll
            for (int i=0;i<2;i++)
#pragma unroll
            for (int j=0;j<4;j++){
                s2[i][j] = MFMA16(oa[i], wh_[j], s2[i][j]);
                s2[i][j] = MFMA16(oa[i], wl_[j], s2[i][j]);
            }
        }
#pragma unroll
        for (int i=0;i<2;i++)
#pragma unroll
        for (int j=0;j<4;j++)
#pragma unroll
        for (int q=0;q<4;q++){
            int t = i*16 + g*4 + q;
            int n = wave*64 + j*16 + r;
            yB[t*YS+n] = f2bf(gelu_f(s2[i][j][q] + b1[n]));
        }
    }
    __syncthreads();   // f (in yB) done
    // Stage 3: hnew[32][128] = f @ w2^T + b2  (K=256) -> global plane
    {
        f32x4 s3[2][2];
#pragma unroll
        for (int i=0;i<2;i++)
#pragma unroll
            for (int j=0;j<2;j++) s3[i][j] = (f32x4){0.f,0.f,0.f,0.f};
#pragma unroll
        for (int ks=0;ks<8;ks++){
            short8 fa[2];
#pragma unroll
            for (int i=0;i<2;i++)
                fa[i] = *(const short8*)&yB[(i*16+r)*YS + ks*32 + g*8];
            short8 wh_[2], wl_[2];
#pragma unroll
            for (int j=0;j<2;j++){
                size_t wa = (size_t)(wave*32 + j*16 + r)*256 + ks*32 + g*8;
                wh_[j] = *(const short8*)&w2h[wa];
                wl_[j] = *(const short8*)&w2l[wa];
            }
#pragma unroll
            for (int i=0;i<2;i++)
#pragma unroll
            for (int j=0;j<2;j++){
                s3[i][j] = MFMA16(fa[i], wh_[j], s3[i][j]);
                s3[i][j] = MFMA16(fa[i], wl_[j], s3[i][j]);
            }
        }
#pragma unroll
        for (int i=0;i<2;i++)
#pragma unroll
        for (int j=0;j<2;j++)
#pragma unroll
        for (int q=0;q<4;q++){
            int t = i*16 + g*4 + q;
            int n = wave*32 + j*16 + r;
            hB[(size_t)(mbase + t)*DM + n] = f2bf(s3[i][j][q] + b2[n]);
        }
    }
}

// ---------------------------------------------------------------------------
// Final transpose: out[bv, d, n] = h[bv*1024+n, d]
__global__ __launch_bounds__(256) void final_transpose(
    const ushort_t* __restrict__ hB, float* __restrict__ out)
{
    int n0 = blockIdx.x*32, d0 = blockIdx.y*32, bv = blockIdx.z;
    __shared__ float ts[32][33];
    int tid = threadIdx.x;
    int c = tid & 31, r0 = tid >> 5;
    for (int rr = r0; rr < 32; rr += 8)
        ts[rr][c] = bf2f(hB[(size_t)(bv*TSEQ + n0 + rr)*DM + d0 + c]);
    __syncthreads();
    for (int rr = r0; rr < 32; rr += 8)
        out[(size_t)(bv*DM + d0 + rr)*TSEQ + n0 + c] = ts[c][rr];
}

// ---------------------------------------------------------------------------
extern "C" void kernel_launch(void* const* d_in, const int* in_sizes, int n_in,
                              void* d_out, int out_size, void* d_ws, size_t ws_size,
                              hipStream_t stream)
{
    const float* x     = (const float*)d_in[0];
    const float* Wp    = (const float*)d_in[1];
    const float* Wpb   = (const float*)d_in[2];
    const float* inW   = (const float*)d_in[3];
    const float* convW = (const float*)d_in[4];
    const float* convB = (const float*)d_in[5];
    const float* xpW   = (const float*)d_in[6];
    const float* dtW   = (const float*)d_in[7];
    const float* dtB   = (const float*)d_in[8];
    const float* Alog  = (const float*)d_in[9];
    const float* Dp    = (const float*)d_in[10];
    const float* outW  = (const float*)d_in[11];
    const float* l1W   = (const float*)d_in[12];
    const float* l1B   = (const float*)d_in[13];
    const float* l2W   = (const float*)d_in[14];
    const float* l2B   = (const float*)d_in[15];
    float* out = (float*)d_out;

    char* base = (char*)d_ws;
    size_t off = 0;
    auto alloc = [&](size_t bytes) { char* p = base + off; off += (bytes + 255) & ~(size_t)255; return p; };

    const size_t P128 = (size_t)MTOK*DM*2;     // [M][128] bf16 plane
    const size_t P256 = (size_t)MTOK*DI*2;     // [M][256] bf16 plane

    ushort_t* hB  = (ushort_t*)alloc(P128);
    // slab1: xin plane (16.8MB) UNION xdc fp32 (37.75MB)
    char* slab1 = alloc((size_t)MTOK*XDW*4);
    ushort_t* xinB = (ushort_t*)slab1;
    float*    xdc  = (float*)slab1;
    ushort_t* zB  = (ushort_t*)alloc(P256);
    ushort_t* xcB = (ushort_t*)alloc(P256);
    float* hloc   = (float*)alloc((size_t)BSEQ*NCH*DS*DI*4);
    float* hstart = (float*)alloc((size_t)BSEQ*NCH*DS*DI*4);
    float* sd     = (float*)alloc((size_t)BSEQ*NCH*DI*4);
    ushort_t* inWh  = (ushort_t*)alloc((size_t)512*128*2);
    ushort_t* inWl  = (ushort_t*)alloc((size_t)512*128*2);
    ushort_t* wcH   = (ushort_t*)alloc((size_t)XDWP*256*2);
    ushort_t* wcL   = (ushort_t*)alloc((size_t)XDWP*256*2);
    ushort_t* outWh = (ushort_t*)alloc((size_t)128*256*2);
    ushort_t* outWl = (ushort_t*)alloc((size_t)128*256*2);
    ushort_t* l1Wh  = (ushort_t*)alloc((size_t)256*128*2);
    ushort_t* l1Wl  = (ushort_t*)alloc((size_t)256*128*2);
    ushort_t* l2Wh  = (ushort_t*)alloc((size_t)128*256*2);
    ushort_t* l2Wl  = (ushort_t*)alloc((size_t)128*256*2);

    patch_embed<<<dim3(32,16), 256, 0, stream>>>(x, Wp, Wpb, hB);

    for (int L = 0; L < L_LAYERS; L++) {
        const float* inW_l   = inW   + (size_t)L*2*DI*DM;
        const float* convW_l = convW + (size_t)L*DI*4;
        const float* convB_l = convB + (size_t)L*DI;
        const float* xpW_l   = xpW   + (size_t)L*(DTR+2*DS)*DI;
        const float* dtW_l   = dtW   + (size_t)L*DI*DTR;
        const float* dtB_l   = dtB   + (size_t)L*DI;
        const float* Alog_l  = Alog  + (size_t)L*DI*DS;
        const float* Dp_l    = Dp    + (size_t)L*DI;
        const float* outW_l  = outW  + (size_t)L*DM*DI;
        const float* l1W_l   = l1W   + (size_t)L*DFF*DM;
        const float* l1B_l   = l1B   + (size_t)L*DFF;
        const float* l2W_l   = l2W   + (size_t)L*DM*DFF;
        const float* l2B_l   = l2B   + (size_t)L*DM;

        // ---- weight prep: ONE dispatch per layer (was 5)
        prep_layer<<<(PREP_ELEMS+255)/256, 256, 0, stream>>>(
            inW_l, xpW_l, dtW_l, outW_l, l1W_l, l2W_l,
            inWh, inWl, wcH, wcL, outWh, outWl, l1Wh, l1Wl, l2Wh, l2Wl);

        // ---- in_proj: [M,512] = h @ inW^T, K=128; routes cols to xin / z
        gemm_stream<128,64,EPI_SPLIT2><<<dim3(MTOK/256, 8), 256, 0, stream>>>(
            hB, inWh, inWl, nullptr, xinB, zB, nullptr);
        // ---- conv + silu
        conv_silu<<<dim3(BSEQ, DI/64, TSEQ/64), 256, 0, stream>>>(
            xinB, convW_l, convB_l, xcB);
        // ---- delta|B|C GEMM: [M,288] = xc @ wc^T, K=256 (softplus on delta)
        // 9 y-tiles: n0 = 0..256 (the n0=288 tile is all pad -> skipped)
        gemm_stream<256,32,EPI_DELTA><<<dim3(MTOK/256, 9), 256, 0, stream>>>(
            xcB, wcH, wcL, dtB_l, nullptr, nullptr, xdc);
        // ---- chunked scan
        scan_pass1<<<dim3(BSEQ, NCH), 256, 0, stream>>>(
            xdc, xcB, Alog_l, hloc, sd);
        scan_combine<<<dim3(BSEQ, DS), 256, 0, stream>>>(
            hloc, sd, Alog_l, hstart);
        // ---- fused scan pass2 + out_proj + FFN
        scan_fused<<<dim3(BSEQ, NCH), 256, 0, stream>>>(
            xdc, xcB, zB, Alog_l, Dp_l, hstart,
            outWh, outWl, l1Wh, l1Wl, l1B_l, l2Wh, l2Wl, l2B_l, hB);
    }

    final_transpose<<<dim3(TSEQ/32, DM/32, BSEQ), 256, 0, stream>>>(hB, out);
}

// Round 13
// 488.878 us; speedup vs baseline: 1.1575x; 1.0234x over previous
//
#include <hip/hip_runtime.h>
#include <math.h>

// Problem constants
#define L_LAYERS 2
#define DM   128
#define DI   256
#define DS   16
#define DTR  8
#define DFF  256
#define PLEN 16
#define BSEQ 32
#define TSEQ 1024
#define MTOK (BSEQ*TSEQ)   // 32768
#define NCH  32            // scan chunks
#define CSZ  32            // TSEQ/NCH
#define XDW  288           // delta(256) | B(16) | C(16)
#define XDWP 320           // padded rows for delta weight

#define EPI_SPLIT2 0
#define EPI_DELTA  3

typedef unsigned short ushort_t;
typedef __attribute__((ext_vector_type(8))) short short8;
typedef __attribute__((ext_vector_type(4))) float f32x4;
#define MFMA16(a,b,c) __builtin_amdgcn_mfma_f32_16x16x32_bf16(a,b,c,0,0,0)

__device__ __forceinline__ float silu_f(float x){ return x / (1.f + __expf(-x)); }
__device__ __forceinline__ float gelu_f(float x){ return 0.5f*x*(1.f + erff(x*0.7071067811865475f)); }
__device__ __forceinline__ float softplus_f(float x){ return (x > 20.f) ? x : log1pf(__expf(x)); }

__device__ __forceinline__ ushort_t f2bf(float f){
    unsigned int u = __float_as_uint(f);
    u += 0x7fffu + ((u >> 16) & 1u);
    return (ushort_t)(u >> 16);
}
__device__ __forceinline__ float bf2f(ushort_t h){
    return __uint_as_float(((unsigned int)h) << 16);
}

// Check A[s] ~= A[0]*(s+1) (true for the reference A_log = log(1..16) tiled).
__device__ __forceinline__ bool a_structured(const float* A){
    bool ok = (A[0] < 0.f);
#pragma unroll
    for (int s=1;s<16;s++){
        float r = A[s]/A[0];
        ok = ok && (fabsf(r - (float)(s+1)) <= 1e-3f);
    }
    return ok;
}

// pk[s] = p^(s+1), log-depth multiply ladder (registers only)
__device__ __forceinline__ void pk_ladder(float p, float* pk){
    float p2 = p*p;
    float p3 = p2*p;
    float p4 = p2*p2;
    float p5 = p4*p, p6 = p4*p2, p7 = p4*p3, p8 = p4*p4;
    pk[0]=p;  pk[1]=p2; pk[2]=p3; pk[3]=p4;
    pk[4]=p5; pk[5]=p6; pk[6]=p7; pk[7]=p8;
    pk[8]=p8*p;  pk[9]=p8*p2;  pk[10]=p8*p3;  pk[11]=p8*p4;
    pk[12]=p8*p5; pk[13]=p8*p6; pk[14]=p8*p7; pk[15]=p8*p8;
}

// ---------------------------------------------------------------------------
// Patch embedding -> h (single bf16 plane)
__global__ __launch_bounds__(256) void patch_embed(
    const float* __restrict__ x, const float* __restrict__ Wp,
    const float* __restrict__ bp, ushort_t* __restrict__ hB)
{
    int bv = blockIdx.x, n0 = blockIdx.y * 64;
    __shared__ float xs[PLEN][64];
    __shared__ float ws[PLEN][DM];
    __shared__ float bs[DM];
    int tid = threadIdx.x;
    {
        int c = tid & 63, r0 = tid >> 6;
        for (int p = r0; p < PLEN; p += 4)
            xs[p][c] = x[bv*(PLEN*TSEQ) + p*TSEQ + n0 + c];
    }
    for (int i = tid; i < DM*PLEN; i += 256) {
        int d = i >> 4, p = i & 15;
        ws[p][d] = Wp[i];
    }
    if (tid < DM) bs[tid] = bp[tid];
    __syncthreads();
    int tm = tid & 15;
    int tn = tid >> 4;
    float acc[4][8];
#pragma unroll
    for (int i=0;i<4;i++)
#pragma unroll
        for (int j=0;j<8;j++) acc[i][j] = bs[tn*8+j];
#pragma unroll
    for (int p=0;p<PLEN;p++) {
        float4 a = *(const float4*)&xs[p][tm*4];
        float4 w0 = *(const float4*)&ws[p][tn*8];
        float4 w1 = *(const float4*)&ws[p][tn*8+4];
        const float* ap = (const float*)&a;
        const float* wp0 = (const float*)&w0;
        const float* wp1 = (const float*)&w1;
#pragma unroll
        for (int i=0;i<4;i++){
#pragma unroll
            for (int j=0;j<4;j++){
                acc[i][j]   += ap[i]*wp0[j];
                acc[i][j+4] += ap[i]*wp1[j];
            }
        }
    }
#pragma unroll
    for (int i=0;i<4;i++){
        size_t row = (size_t)(bv*TSEQ + n0 + tm*4 + i)*DM + tn*8;
        short8 hv;
#pragma unroll
        for (int j=0;j<8;j++) hv[j] = (short)f2bf(acc[i][j]);
        *(short8*)&hB[row] = hv;
    }
}

// ---------------------------------------------------------------------------
// One-dispatch per-layer weight prep: fp32 -> bf16 hi/lo planes for
// inW (65536) | combined x_proj 320x256 (81920) | outW (32768) |
// l1W (32768) | l2W (32768). Total 245760 elements.
#define PREP_ELEMS 245760
__global__ __launch_bounds__(256) void prep_layer(
    const float* __restrict__ inW, const float* __restrict__ xpW,
    const float* __restrict__ dtW, const float* __restrict__ outW,
    const float* __restrict__ l1W, const float* __restrict__ l2W,
    ushort_t* __restrict__ inWh, ushort_t* __restrict__ inWl,
    ushort_t* __restrict__ wcH,  ushort_t* __restrict__ wcL,
    ushort_t* __restrict__ outWh,ushort_t* __restrict__ outWl,
    ushort_t* __restrict__ l1Wh, ushort_t* __restrict__ l1Wl,
    ushort_t* __restrict__ l2Wh, ushort_t* __restrict__ l2Wl)
{
    int e = blockIdx.x*256 + threadIdx.x;
    if (e >= PREP_ELEMS) return;
    float v; ushort_t *dh, *dl; int o;
    if (e < 65536){
        v = inW[e]; dh = inWh; dl = inWl; o = e;
    } else if (e < 147456){
        int ee = e - 65536;           // 0..81919
        int n = ee >> 8, k = ee & 255;
        if (n < 256){
            v = 0.f;
#pragma unroll
            for (int r=0;r<8;r++) v += dtW[n*8+r]*xpW[r*256+k];
        } else if (n < XDW){
            v = xpW[(n-256+DTR)*256 + k];
        } else {
            v = 0.f;
        }
        dh = wcH; dl = wcL; o = ee;
    } else if (e < 180224){
        int ee = e - 147456; v = outW[ee]; dh = outWh; dl = outWl; o = ee;
    } else if (e < 212992){
        int ee = e - 180224; v = l1W[ee]; dh = l1Wh; dl = l1Wl; o = ee;
    } else {
        int ee = e - 212992; v = l2W[ee]; dh = l2Wh; dl = l2Wl; o = ee;
    }
    ushort_t hi = f2bf(v);
    dh[o] = hi;
    dl[o] = f2bf(v - bf2f(hi));
}

// ---------------------------------------------------------------------------
// Fused in_proj GEMM + causal depthwise conv (width 4) + bias + SiLU.
// grid (MTOK/256, 8): n-tiles 0..3 -> xin channels (conv applied, write xcB);
// n-tiles 4..7 -> z channels (plain bf16 store to zB).
// LDS: sW (32 KB, K-loop) UNION xs[259][68] bf16 xin tile (35.2 KB) + conv
// coeffs. Batch starts align with m-tiles (1024 % 256 == 0), so the 3
// conv history rows are either zero (batch start) or recomputed cheaply.
__global__ __launch_bounds__(256) void gemm_inproj_conv(
    const ushort_t* __restrict__ A,
    const ushort_t* __restrict__ WH, const ushort_t* __restrict__ WL,
    const float* __restrict__ cw, const float* __restrict__ cb,
    ushort_t* __restrict__ xcB, ushort_t* __restrict__ zB)
{
    constexpr int KT = 128, NT = 64, NCHK = KT/8;
    constexpr int XSS = 68;                     // xs row stride (shorts)
    __shared__ __align__(16) char smem[259*XSS*2 + 64*5*4 + 64*4];
    ushort_t* sWh = (ushort_t*)smem;            // 8192 shorts
    ushort_t* sWl = sWh + NT*KT;                // 8192 shorts
    ushort_t* xs  = (ushort_t*)smem;            // union with sW (after barrier)
    float* cws = (float*)(smem + 259*XSS*2);    // [c*5+k]
    float* cbs = cws + 64*5;

    int m0 = blockIdx.x*256, n0 = blockIdx.y*NT;
    bool is_x = (n0 < 256);
    int tid = threadIdx.x;
    for (int i = tid; i < NT*NCHK; i += 256) {
        int nrow = i / NCHK, c = i % NCHK;
        int cs = c ^ (nrow & 7);
        *(short8*)&sWh[nrow*KT + cs*8] = *(const short8*)&WH[(size_t)(n0+nrow)*KT + c*8];
        *(short8*)&sWl[nrow*KT + cs*8] = *(const short8*)&WL[(size_t)(n0+nrow)*KT + c*8];
    }
    if (is_x){
        { int c = tid >> 2, k = tid & 3; cws[c*5+k] = cw[(n0+c)*4 + k]; }
        if (tid < 64) cbs[tid] = cb[n0+tid];
    }
    __syncthreads();
    int wave = tid>>6, lane = tid&63;
    int r = lane&15, g = lane>>4;
    int mw = m0 + wave*64;
    f32x4 acc[4][4];
#pragma unroll
    for (int i=0;i<4;i++)
#pragma unroll
        for (int j=0;j<4;j++) acc[i][j] = (f32x4){0.f,0.f,0.f,0.f};
#pragma unroll
    for (int ks = 0; ks < KT/32; ks++){
        short8 ah[4];
#pragma unroll
        for (int i=0;i<4;i++){
            size_t ga = (size_t)(mw + i*16 + r)*KT + ks*32 + g*8;
            ah[i] = *(const short8*)&A[ga];
        }
        short8 wh[4], wl[4];
#pragma unroll
        for (int j=0;j<4;j++){
            int nrow = j*16 + r;
            int cs = (ks*4 + g) ^ (nrow & 7);
            wh[j] = *(const short8*)&sWh[nrow*KT + cs*8];
            wl[j] = *(const short8*)&sWl[nrow*KT + cs*8];
        }
#pragma unroll
        for (int i=0;i<4;i++)
#pragma unroll
        for (int j=0;j<4;j++){
            acc[i][j] = MFMA16(ah[i], wh[j], acc[i][j]);
            acc[i][j] = MFMA16(ah[i], wl[j], acc[i][j]);
        }
    }
    if (!is_x){
        // z epilogue: plain bf16 store
#pragma unroll
        for (int i=0;i<4;i++)
#pragma unroll
        for (int j=0;j<4;j++)
#pragma unroll
        for (int q=0;q<4;q++){
            int mm = mw + i*16 + g*4 + q;
            int nn = n0 - 256 + j*16 + r;
            zB[(size_t)mm*DI + nn] = f2bf(acc[i][j][q]);
        }
        return;
    }
    // Boundary rows (tokens m0-3..m0-1): recompute xin via scalar dot from
    // global (W is L2-hot). Zero at batch starts (m0 % 1024 == 0).
    float bacc = 0.f;
    bool bvalid = ((m0 & 1023) != 0);
    if (tid < 192 && bvalid){
        int brow = tid >> 6, bcol = tid & 63;
        const ushort_t* hrow = A  + (size_t)(m0 - 3 + brow)*KT;
        const ushort_t* wrh  = WH + (size_t)(n0 + bcol)*KT;
        const ushort_t* wrl  = WL + (size_t)(n0 + bcol)*KT;
#pragma unroll 8
        for (int k=0;k<KT;k++)
            bacc += bf2f(hrow[k]) * (bf2f(wrh[k]) + bf2f(wrl[k]));
    }
    __syncthreads();   // all sW reads done -> safe to overwrite with xs
    if (tid < 192){
        int brow = tid >> 6, bcol = tid & 63;
        xs[brow*XSS + bcol] = bvalid ? f2bf(bacc) : (ushort_t)0;
    }
#pragma unroll
    for (int i=0;i<4;i++)
#pragma unroll
    for (int j=0;j<4;j++)
#pragma unroll
    for (int q=0;q<4;q++){
        int mm = mw + i*16 + g*4 + q;
        xs[(mm - m0 + 3)*XSS + j*16 + r] = f2bf(acc[i][j][q]);
    }
    __syncthreads();
    // Conv + SiLU + store: one wave handles one token row per iteration
    for (int p = 0; p < 64; p++){
        int idx = p*256 + tid;
        int t = idx >> 6, cl = idx & 63;
        float v = cbs[cl];
#pragma unroll
        for (int k=0;k<4;k++) v += cws[cl*5+k]*bf2f(xs[(t+k)*XSS + cl]);
        xcB[(size_t)(m0 + t)*DI + n0 + cl] = f2bf(silu_f(v));
    }
}

// ---------------------------------------------------------------------------
// Streaming MFMA GEMM: C[M,*] = A[M,KT] @ W[*,KT]^T
// A single bf16 plane; W split hi/lo (2-term). Weights cached in LDS once
// (XOR-swizzled); K-loop barrier-free; A streamed from global (L3-resident).
template<int KT, int NT, int EPI>
__global__ __launch_bounds__(256) void gemm_stream(
    const ushort_t* __restrict__ A,
    const ushort_t* __restrict__ WH, const ushort_t* __restrict__ WL,
    const float* __restrict__ bias,
    ushort_t* __restrict__ o1, ushort_t* __restrict__ o2,
    float* __restrict__ CF)
{
    constexpr int NCHK = KT/8;
    constexpr int NF = NT/16;
    __shared__ ushort_t sWh[NT*KT];
    __shared__ ushort_t sWl[NT*KT];
    int m0 = blockIdx.x*256, n0 = blockIdx.y*NT;
    int tid = threadIdx.x;
    for (int i = tid; i < NT*NCHK; i += 256) {
        int nrow = i / NCHK, c = i % NCHK;
        int cs = c ^ (nrow & 7);
        *(short8*)&sWh[nrow*KT + cs*8] = *(const short8*)&WH[(size_t)(n0+nrow)*KT + c*8];
        *(short8*)&sWl[nrow*KT + cs*8] = *(const short8*)&WL[(size_t)(n0+nrow)*KT + c*8];
    }
    __syncthreads();
    int wave = tid>>6, lane = tid&63;
    int r = lane&15, g = lane>>4;
    int mw = m0 + wave*64;
    f32x4 acc[4][NF];
#pragma unroll
    for (int i=0;i<4;i++)
#pragma unroll
        for (int j=0;j<NF;j++) acc[i][j] = (f32x4){0.f,0.f,0.f,0.f};

#pragma unroll
    for (int ks = 0; ks < KT/32; ks++){
        short8 ah[4];
#pragma unroll
        for (int i=0;i<4;i++){
            size_t ga = (size_t)(mw + i*16 + r)*KT + ks*32 + g*8;
            ah[i] = *(const short8*)&A[ga];
        }
        short8 wh[NF], wl[NF];
#pragma unroll
        for (int j=0;j<NF;j++){
            int nrow = j*16 + r;
            int cs = (ks*4 + g) ^ (nrow & 7);
            wh[j] = *(const short8*)&sWh[nrow*KT + cs*8];
            wl[j] = *(const short8*)&sWl[nrow*KT + cs*8];
        }
#pragma unroll
        for (int i=0;i<4;i++)
#pragma unroll
        for (int j=0;j<NF;j++){
            acc[i][j] = MFMA16(ah[i], wh[j], acc[i][j]);
            acc[i][j] = MFMA16(ah[i], wl[j], acc[i][j]);
        }
    }
#pragma unroll
    for (int i=0;i<4;i++){
#pragma unroll
        for (int j=0;j<NF;j++){
            int nn = n0 + j*16 + r;
#pragma unroll
            for (int q=0;q<4;q++){
                int mm = mw + i*16 + g*4 + q;
                float v = acc[i][j][q];
                if (EPI == EPI_DELTA){
                    if (nn < XDW){
                        if (nn < 256) v = softplus_f(v + bias[nn]);
                        CF[(size_t)mm*XDW + nn] = v;
                    }
                } else {
                    ushort_t hv = f2bf(v);
                    if (nn < 256) o1[(size_t)mm*256 + nn] = hv;
                    else          o2[(size_t)mm*256 + nn-256] = hv;
                }
            }
        }
    }
}

// ---------------------------------------------------------------------------
// Scan pass 1: per (b, chunk, d): local end-state (h_start=0) and sum(delta)
// 8-deep load prefetch per group.
__global__ __launch_bounds__(256) void scan_pass1(
    const float* __restrict__ xdc, const ushort_t* __restrict__ xcB,
    const float* __restrict__ Alog,
    float* __restrict__ hloc, float* __restrict__ sd)
{
    int b = blockIdx.x, c = blockIdx.y;
    int d = threadIdx.x;
    __shared__ float Bs[CSZ][16];
    int mbase = b*TSEQ + c*CSZ;
    for (int i = d; i < CSZ*16; i += 256) {
        int t = i >> 4, s = i & 15;
        Bs[t][s] = xdc[(size_t)(mbase+t)*XDW + 256 + s];
    }
    float A[16], h[16];
    {
        float4 a0 = *(const float4*)&Alog[d*16];
        float4 a1 = *(const float4*)&Alog[d*16+4];
        float4 a2 = *(const float4*)&Alog[d*16+8];
        float4 a3 = *(const float4*)&Alog[d*16+12];
        float tmp[16] = {a0.x,a0.y,a0.z,a0.w,a1.x,a1.y,a1.z,a1.w,
                         a2.x,a2.y,a2.z,a2.w,a3.x,a3.y,a3.z,a3.w};
#pragma unroll
        for (int s=0;s<16;s++){ A[s] = -__expf(tmp[s]); h[s] = 0.f; }
    }
    bool structured = a_structured(A);
    float A0 = A[0];
    float sdv = 0.f;
    __syncthreads();
    for (int t0 = 0; t0 < CSZ; t0 += 8){
        float dl[8], uu[8];
#pragma unroll
        for (int k=0;k<8;k++){
            size_t m = (size_t)(mbase+t0+k);
            dl[k] = xdc[m*XDW + d];
            uu[k] = bf2f(xcB[m*DI + d]);
        }
        if (structured) {
#pragma unroll
            for (int k=0;k<8;k++){
                int t = t0+k;
                float dlt = dl[k];
                sdv += dlt;
                float du = dlt*uu[k];
                float pk[16];
                pk_ladder(__expf(dlt*A0), pk);
#pragma unroll
                for (int s=0;s<16;s++)
                    h[s] = pk[s]*h[s] + du*Bs[t][s];
            }
        } else {
#pragma unroll
            for (int k=0;k<8;k++){
                int t = t0+k;
                float dlt = dl[k];
                sdv += dlt;
                float du = dlt*uu[k];
#pragma unroll
                for (int s=0;s<16;s++)
                    h[s] = __expf(dlt*A[s])*h[s] + du*Bs[t][s];
            }
        }
    }
#pragma unroll
    for (int s=0;s<16;s++)
        hloc[((size_t)((b*NCH + c)*16 + s))*DI + d] = h[s];
    sd[(b*NCH + c)*DI + d] = sdv;
}

// ---------------------------------------------------------------------------
// Prefix-combine over chunks (thread = (b,s,d))
__global__ __launch_bounds__(256) void scan_combine(
    const float* __restrict__ hloc, const float* __restrict__ sd,
    const float* __restrict__ Alog, float* __restrict__ hstart)
{
    int b = blockIdx.x, s = blockIdx.y;
    int d = threadIdx.x;
    float A = -__expf(Alog[d*16+s]);
    float hs = 0.f;
    for (int c = 0; c < NCH; c++){
        size_t base = ((size_t)((b*NCH + c)*16 + s))*DI + d;
        hstart[base] = hs;
        float sdp = sd[(b*NCH + c)*DI + d];
        hs = __expf(sdp*A)*hs + hloc[base];
    }
}

// ---------------------------------------------------------------------------
// Fused scan pass 2 + out_proj + FFN (gelu) for a 32-token chunk.
// Single-plane activations; Phase A uses 8-deep load prefetch.
// LDS: yB [32][264] bf16 (16896 B);
// region2 = union( oB [32][136] bf16 (8704 B), Bs/Cs fp32 (4096 B) ).
// Total 25600 B.
__global__ __launch_bounds__(256,3) void scan_fused(
    const float* __restrict__ xdc,
    const ushort_t* __restrict__ xcB, const ushort_t* __restrict__ zB,
    const float* __restrict__ Alog, const float* __restrict__ Dp,
    const float* __restrict__ hstart,
    const ushort_t* __restrict__ oWh, const ushort_t* __restrict__ oWl,
    const ushort_t* __restrict__ w1h, const ushort_t* __restrict__ w1l,
    const float* __restrict__ b1,
    const ushort_t* __restrict__ w2h, const ushort_t* __restrict__ w2l,
    const float* __restrict__ b2,
    ushort_t* __restrict__ hB)
{
    constexpr int YS = DI + 8;    // 264 shorts (row stride 528 B, 16-aligned)
    constexpr int OS = DM + 8;    // 136 shorts
    __shared__ __align__(16) ushort_t smem[CSZ*YS + CSZ*OS];   // 25600 B
    ushort_t* yB = smem;                      // [t*YS + d]
    ushort_t* oB = smem + CSZ*YS;             // [t*OS + n]
    float*    Bs = (float*)(smem + CSZ*YS);   // union with oB
    float*    Cs = Bs + CSZ*16;

    int b = blockIdx.x, c = blockIdx.y;
    int tid = threadIdx.x;
    int mbase = b*TSEQ + c*CSZ;
    for (int i = tid; i < CSZ*32; i += 256) {
        int t = i >> 5, s2 = i & 31;
        float v = xdc[(size_t)(mbase+t)*XDW + 256 + s2];
        if (s2 < 16) Bs[t*16+s2] = v; else Cs[t*16+s2-16] = v;
    }
    // ---- Phase A: scan
    {
        int d = tid;
        float A[16], h[16];
        float4 a0 = *(const float4*)&Alog[d*16];
        float4 a1 = *(const float4*)&Alog[d*16+4];
        float4 a2 = *(const float4*)&Alog[d*16+8];
        float4 a3 = *(const float4*)&Alog[d*16+12];
        float tmp[16] = {a0.x,a0.y,a0.z,a0.w,a1.x,a1.y,a1.z,a1.w,
                         a2.x,a2.y,a2.z,a2.w,a3.x,a3.y,a3.z,a3.w};
#pragma unroll
        for (int s=0;s<16;s++) A[s] = -__expf(tmp[s]);
        bool structured = a_structured(A);
        float A0 = A[0];
#pragma unroll
        for (int s=0;s<16;s++)
            h[s] = hstart[((size_t)((b*NCH + c)*16 + s))*DI + d];
        float Dd = Dp[d];
        __syncthreads();
        for (int t0 = 0; t0 < CSZ; t0 += 8){
            float dl[8], uu[8], zz[8];
#pragma unroll
            for (int k=0;k<8;k++){
                size_t m = (size_t)(mbase+t0+k);
                dl[k] = xdc[m*XDW + d];
                uu[k] = bf2f(xcB[m*DI + d]);
                zz[k] = bf2f(zB[m*DI + d]);
            }
            if (structured) {
#pragma unroll
                for (int k=0;k<8;k++){
                    int t = t0+k;
                    float dlt = dl[k];
                    float u = uu[k];
                    float du = dlt*u;
                    float pk[16];
                    pk_ladder(__expf(dlt*A0), pk);
                    float y0=0.f, y1=0.f, y2=0.f, y3=0.f;
#pragma unroll
                    for (int s=0;s<16;s+=4){
                        h[s]   = pk[s]*h[s]     + du*Bs[t*16+s];   y0 += h[s]*Cs[t*16+s];
                        h[s+1] = pk[s+1]*h[s+1] + du*Bs[t*16+s+1]; y1 += h[s+1]*Cs[t*16+s+1];
                        h[s+2] = pk[s+2]*h[s+2] + du*Bs[t*16+s+2]; y2 += h[s+2]*Cs[t*16+s+2];
                        h[s+3] = pk[s+3]*h[s+3] + du*Bs[t*16+s+3]; y3 += h[s+3]*Cs[t*16+s+3];
                    }
                    float y = (y0+y1)+(y2+y3);
                    yB[t*YS+d] = f2bf((y + u*Dd) * silu_f(zz[k]));
                }
            } else {
#pragma unroll
                for (int k=0;k<8;k++){
                    int t = t0+k;
                    float dlt = dl[k];
                    float u = uu[k];
                    float du = dlt*u;
                    float y0=0.f, y1=0.f, y2=0.f, y3=0.f;
#pragma unroll
                    for (int s=0;s<16;s+=4){
                        h[s]   = __expf(dlt*A[s])*h[s]     + du*Bs[t*16+s];   y0 += h[s]*Cs[t*16+s];
                        h[s+1] = __expf(dlt*A[s+1])*h[s+1] + du*Bs[t*16+s+1]; y1 += h[s+1]*Cs[t*16+s+1];
                        h[s+2] = __expf(dlt*A[s+2])*h[s+2] + du*Bs[t*16+s+2]; y2 += h[s+2]*Cs[t*16+s+2];
                        h[s+3] = __expf(dlt*A[s+3])*h[s+3] + du*Bs[t*16+s+3]; y3 += h[s+3]*Cs[t*16+s+3];
                    }
                    float y = (y0+y1)+(y2+y3);
                    yB[t*YS+d] = f2bf((y + u*Dd) * silu_f(zz[k]));
                }
            }
        }
    }
    __syncthreads();   // yB done; Bs/Cs dead -> region2 reusable as oB
    // ---- Phase B
    int wave = tid>>6, lane = tid&63;
    int r = lane&15, g = lane>>4;
    // Stage 1: o[32][128] = y @ oW^T  (K=256)
    {
        f32x4 s1[2][2];
#pragma unroll
        for (int i=0;i<2;i++)
#pragma unroll
            for (int j=0;j<2;j++) s1[i][j] = (f32x4){0.f,0.f,0.f,0.f};
#pragma unroll
        for (int ks=0;ks<8;ks++){
            short8 ya[2];
#pragma unroll
            for (int i=0;i<2;i++)
                ya[i] = *(const short8*)&yB[(i*16+r)*YS + ks*32 + g*8];
            short8 wh_[2], wl_[2];
#pragma unroll
            for (int j=0;j<2;j++){
                size_t wa = (size_t)(wave*32 + j*16 + r)*256 + ks*32 + g*8;
                wh_[j] = *(const short8*)&oWh[wa];
                wl_[j] = *(const short8*)&oWl[wa];
            }
#pragma unroll
            for (int i=0;i<2;i++)
#pragma unroll
            for (int j=0;j<2;j++){
                s1[i][j] = MFMA16(ya[i], wh_[j], s1[i][j]);
                s1[i][j] = MFMA16(ya[i], wl_[j], s1[i][j]);
            }
        }
#pragma unroll
        for (int i=0;i<2;i++)
#pragma unroll
        for (int j=0;j<2;j++)
#pragma unroll
        for (int q=0;q<4;q++){
            int t = i*16 + g*4 + q;
            int n = wave*32 + j*16 + r;
            oB[t*OS+n] = f2bf(s1[i][j][q]);
        }
    }
    __syncthreads();   // oB ready; yB reads done
    // Stage 2: f[32][256] = gelu(o @ w1^T + b1)  (K=128), into yB
    {
        f32x4 s2[2][4];
#pragma unroll
        for (int i=0;i<2;i++)
#pragma unroll
            for (int j=0;j<4;j++) s2[i][j] = (f32x4){0.f,0.f,0.f,0.f};
#pragma unroll
        for (int ks=0;ks<4;ks++){
            short8 oa[2];
#pragma unroll
            for (int i=0;i<2;i++)
                oa[i] = *(const short8*)&oB[(i*16+r)*OS + ks*32 + g*8];
            short8 wh_[4], wl_[4];
#pragma unroll
            for (int j=0;j<4;j++){
                size_t wa = (size_t)(wave*64 + j*16 + r)*128 + ks*32 + g*8;
                wh_[j] = *(const short8*)&w1h[wa];
                wl_[j] = *(const short8*)&w1l[wa];
            }
#pragma unroll
            for (int i=0;i<2;i++)
#pragma unroll
            for (int j=0;j<4;j++){
                s2[i][j] = MFMA16(oa[i], wh_[j], s2[i][j]);
                s2[i][j] = MFMA16(oa[i], wl_[j], s2[i][j]);
            }
        }
#pragma unroll
        for (int i=0;i<2;i++)
#pragma unroll
        for (int j=0;j<4;j++)
#pragma unroll
        for (int q=0;q<4;q++){
            int t = i*16 + g*4 + q;
            int n = wave*64 + j*16 + r;
            yB[t*YS+n] = f2bf(gelu_f(s2[i][j][q] + b1[n]));
        }
    }
    __syncthreads();   // f (in yB) done
    // Stage 3: hnew[32][128] = f @ w2^T + b2  (K=256) -> global plane
    {
        f32x4 s3[2][2];
#pragma unroll
        for (int i=0;i<2;i++)
#pragma unroll
            for (int j=0;j<2;j++) s3[i][j] = (f32x4){0.f,0.f,0.f,0.f};
#pragma unroll
        for (int ks=0;ks<8;ks++){
            short8 fa[2];
#pragma unroll
            for (int i=0;i<2;i++)
                fa[i] = *(const short8*)&yB[(i*16+r)*YS + ks*32 + g*8];
            short8 wh_[2], wl_[2];
#pragma unroll
            for (int j=0;j<2;j++){
                size_t wa = (size_t)(wave*32 + j*16 + r)*256 + ks*32 + g*8;
                wh_[j] = *(const short8*)&w2h[wa];
                wl_[j] = *(const short8*)&w2l[wa];
            }
#pragma unroll
            for (int i=0;i<2;i++)
#pragma unroll
            for (int j=0;j<2;j++){
                s3[i][j] = MFMA16(fa[i], wh_[j], s3[i][j]);
                s3[i][j] = MFMA16(fa[i], wl_[j], s3[i][j]);
            }
        }
#pragma unroll
        for (int i=0;i<2;i++)
#pragma unroll
        for (int j=0;j<2;j++)
#pragma unroll
        for (int q=0;q<4;q++){
            int t = i*16 + g*4 + q;
            int n = wave*32 + j*16 + r;
            hB[(size_t)(mbase + t)*DM + n] = f2bf(s3[i][j][q] + b2[n]);
        }
    }
}

// ---------------------------------------------------------------------------
// Final transpose: out[bv, d, n] = h[bv*1024+n, d]
__global__ __launch_bounds__(256) void final_transpose(
    const ushort_t* __restrict__ hB, float* __restrict__ out)
{
    int n0 = blockIdx.x*32, d0 = blockIdx.y*32, bv = blockIdx.z;
    __shared__ float ts[32][33];
    int tid = threadIdx.x;
    int c = tid & 31, r0 = tid >> 5;
    for (int rr = r0; rr < 32; rr += 8)
        ts[rr][c] = bf2f(hB[(size_t)(bv*TSEQ + n0 + rr)*DM + d0 + c]);
    __syncthreads();
    for (int rr = r0; rr < 32; rr += 8)
        out[(size_t)(bv*DM + d0 + rr)*TSEQ + n0 + c] = ts[c][rr];
}

// ---------------------------------------------------------------------------
extern "C" void kernel_launch(void* const* d_in, const int* in_sizes, int n_in,
                              void* d_out, int out_size, void* d_ws, size_t ws_size,
                              hipStream_t stream)
{
    const float* x     = (const float*)d_in[0];
    const float* Wp    = (const float*)d_in[1];
    const float* Wpb   = (const float*)d_in[2];
    const float* inW   = (const float*)d_in[3];
    const float* convW = (const float*)d_in[4];
    const float* convB = (const float*)d_in[5];
    const float* xpW   = (const float*)d_in[6];
    const float* dtW   = (const float*)d_in[7];
    const float* dtB   = (const float*)d_in[8];
    const float* Alog  = (const float*)d_in[9];
    const float* Dp    = (const float*)d_in[10];
    const float* outW  = (const float*)d_in[11];
    const float* l1W   = (const float*)d_in[12];
    const float* l1B   = (const float*)d_in[13];
    const float* l2W   = (const float*)d_in[14];
    const float* l2B   = (const float*)d_in[15];
    float* out = (float*)d_out;

    char* base = (char*)d_ws;
    size_t off = 0;
    auto alloc = [&](size_t bytes) { char* p = base + off; off += (bytes + 255) & ~(size_t)255; return p; };

    const size_t P128 = (size_t)MTOK*DM*2;     // [M][128] bf16 plane
    const size_t P256 = (size_t)MTOK*DI*2;     // [M][256] bf16 plane

    ushort_t* hB  = (ushort_t*)alloc(P128);
    float*    xdc = (float*)alloc((size_t)MTOK*XDW*4);
    ushort_t* zB  = (ushort_t*)alloc(P256);
    ushort_t* xcB = (ushort_t*)alloc(P256);
    float* hloc   = (float*)alloc((size_t)BSEQ*NCH*DS*DI*4);
    float* hstart = (float*)alloc((size_t)BSEQ*NCH*DS*DI*4);
    float* sd     = (float*)alloc((size_t)BSEQ*NCH*DI*4);
    ushort_t* inWh  = (ushort_t*)alloc((size_t)512*128*2);
    ushort_t* inWl  = (ushort_t*)alloc((size_t)512*128*2);
    ushort_t* wcH   = (ushort_t*)alloc((size_t)XDWP*256*2);
    ushort_t* wcL   = (ushort_t*)alloc((size_t)XDWP*256*2);
    ushort_t* outWh = (ushort_t*)alloc((size_t)128*256*2);
    ushort_t* outWl = (ushort_t*)alloc((size_t)128*256*2);
    ushort_t* l1Wh  = (ushort_t*)alloc((size_t)256*128*2);
    ushort_t* l1Wl  = (ushort_t*)alloc((size_t)256*128*2);
    ushort_t* l2Wh  = (ushort_t*)alloc((size_t)128*256*2);
    ushort_t* l2Wl  = (ushort_t*)alloc((size_t)128*256*2);

    patch_embed<<<dim3(32,16), 256, 0, stream>>>(x, Wp, Wpb, hB);

    for (int L = 0; L < L_LAYERS; L++) {
        const float* inW_l   = inW   + (size_t)L*2*DI*DM;
        const float* convW_l = convW + (size_t)L*DI*4;
        const float* convB_l = convB + (size_t)L*DI;
        const float* xpW_l   = xpW   + (size_t)L*(DTR+2*DS)*DI;
        const float* dtW_l   = dtW   + (size_t)L*DI*DTR;
        const float* dtB_l   = dtB   + (size_t)L*DI;
        const float* Alog_l  = Alog  + (size_t)L*DI*DS;
        const float* Dp_l    = Dp    + (size_t)L*DI;
        const float* outW_l  = outW  + (size_t)L*DM*DI;
        const float* l1W_l   = l1W   + (size_t)L*DFF*DM;
        const float* l1B_l   = l1B   + (size_t)L*DFF;
        const float* l2W_l   = l2W   + (size_t)L*DM*DFF;
        const float* l2B_l   = l2B   + (size_t)L*DM;

        // ---- weight prep: ONE dispatch per layer
        prep_layer<<<(PREP_ELEMS+255)/256, 256, 0, stream>>>(
            inW_l, xpW_l, dtW_l, outW_l, l1W_l, l2W_l,
            inWh, inWl, wcH, wcL, outWh, outWl, l1Wh, l1Wl, l2Wh, l2Wl);

        // ---- fused in_proj GEMM + causal conv + SiLU (xin never hits HBM)
        gemm_inproj_conv<<<dim3(MTOK/256, 8), 256, 0, stream>>>(
            hB, inWh, inWl, convW_l, convB_l, xcB, zB);
        // ---- delta|B|C GEMM: [M,288] = xc @ wc^T, K=256 (softplus on delta)
        gemm_stream<256,32,EPI_DELTA><<<dim3(MTOK/256, 9), 256, 0, stream>>>(
            xcB, wcH, wcL, dtB_l, nullptr, nullptr, xdc);
        // ---- chunked scan
        scan_pass1<<<dim3(BSEQ, NCH), 256, 0, stream>>>(
            xdc, xcB, Alog_l, hloc, sd);
        scan_combine<<<dim3(BSEQ, DS), 256, 0, stream>>>(
            hloc, sd, Alog_l, hstart);
        // ---- fused scan pass2 + out_proj + FFN
        scan_fused<<<dim3(BSEQ, NCH), 256, 0, stream>>>(
            xdc, xcB, zB, Alog_l, Dp_l, hstart,
            outWh, outWl, l1Wh, l1Wl, l1B_l, l2Wh, l2Wl, l2B_l, hB);
    }

    final_transpose<<<dim3(TSEQ/32, DM/32, BSEQ), 256, 0, stream>>>(hB, out);
}